// Round 1
// baseline (734.917 us; speedup 1.0000x reference)
//
#include <hip/hip_runtime.h>
#include <hip/hip_bf16.h>
#include <math.h>

#define NNODES_HINT 50000

// ---------------------------------------------------------------------------
// CSR build: histogram -> scan -> scatter (group edges by dst, incl self-loops)
// ---------------------------------------------------------------------------

__global__ void init_counts(int* __restrict__ offs, int n) {
    int i = blockIdx.x * blockDim.x + threadIdx.x;
    if (i <= n) offs[i] = (i == 0) ? 0 : 1;   // 1 = self-loop per node
}

__global__ void hist_kernel(const int* __restrict__ ei, int E, int* __restrict__ offs) {
    int i = blockIdx.x * blockDim.x + threadIdx.x;
    if (i < E) {
        int d = ei[E + i];          // dst row of edge_index
        atomicAdd(&offs[1 + d], 1);
    }
}

// Per-block inclusive scan over counts at offs[1..n]
__global__ void scan_local(int* __restrict__ offs, int* __restrict__ blksums, int n) {
    __shared__ int lds[1024];
    int i = 1 + blockIdx.x * 1024 + threadIdx.x;
    int v = (i <= n) ? offs[i] : 0;
    lds[threadIdx.x] = v;
    __syncthreads();
    #pragma unroll
    for (int o = 1; o < 1024; o <<= 1) {
        int t = (threadIdx.x >= o) ? lds[threadIdx.x - o] : 0;
        __syncthreads();
        lds[threadIdx.x] += t;
        __syncthreads();
    }
    if (i <= n) offs[i] = lds[threadIdx.x];
    if (threadIdx.x == 1023) blksums[blockIdx.x] = lds[1023];
}

__global__ void scan_blksums(int* __restrict__ blksums, int nb) {
    int lane = threadIdx.x;   // single wave of 64, nb <= 64
    int v = (lane < nb) ? blksums[lane] : 0;
    #pragma unroll
    for (int o = 1; o < 64; o <<= 1) {
        int t = __shfl_up(v, o);
        if (lane >= o) v += t;
    }
    if (lane < nb) blksums[lane] = v;
}

__global__ void scan_add(int* __restrict__ offs, const int* __restrict__ blksums,
                         int* __restrict__ cursor, int n) {
    int i = 1 + blockIdx.x * 1024 + threadIdx.x;
    if (i > n) return;
    int add = (blockIdx.x > 0) ? blksums[blockIdx.x - 1] : 0;
    int val = offs[i] + add;
    offs[i] = val;
    if (i < n) cursor[i] = val;
    if (i == 1) cursor[0] = 0;
}

__global__ void scatter_kernel(const int* __restrict__ ei, int E, int n,
                               int* __restrict__ cursor, int* __restrict__ srcs) {
    int i = blockIdx.x * blockDim.x + threadIdx.x;
    int total = E + n;
    if (i >= total) return;
    int s, d;
    if (i < E) { s = ei[i]; d = ei[E + i]; }
    else       { s = d = i - E; }            // self loops
    int p = atomicAdd(&cursor[d], 1);
    srcs[p] = s;
}

// ---------------------------------------------------------------------------
// fp32 tiled GEMM: C[M,N] = A[M,K] @ B[K,N]; N multiple of 64, K multiple of 16
// ---------------------------------------------------------------------------
#define BM 64
#define BN 64
#define BK 16
#define BMP 68
#define BNP 68

__global__ __launch_bounds__(256) void sgemm(const float* __restrict__ A,
                                             const float* __restrict__ B,
                                             float* __restrict__ C,
                                             int M, int K, int N) {
    __shared__ float As[BK][BMP];
    __shared__ float Bs[BK][BNP];
    int tid = threadIdx.x;
    int bm0 = blockIdx.x * BM;
    int bn0 = blockIdx.y * BN;

    int arow = tid >> 2;           // 0..63
    int acol = (tid & 3) * 4;      // 0,4,8,12
    int brow = tid >> 4;           // 0..15
    int bcol = (tid & 15) * 4;     // 0..60
    int ty = tid >> 4;             // 0..15  (rows ty*4..+3)
    int tx = tid & 15;             // 0..15  (cols tx*4..+3)

    int ar = bm0 + arow; if (ar > M - 1) ar = M - 1;  // clamp; store is guarded

    float acc[4][4];
    #pragma unroll
    for (int r = 0; r < 4; r++)
        #pragma unroll
        for (int c = 0; c < 4; c++) acc[r][c] = 0.f;

    for (int kt = 0; kt < K; kt += BK) {
        float4 a = *(const float4*)(A + (size_t)ar * K + kt + acol);
        float4 b = *(const float4*)(B + (size_t)(kt + brow) * N + bn0 + bcol);
        As[acol + 0][arow] = a.x;
        As[acol + 1][arow] = a.y;
        As[acol + 2][arow] = a.z;
        As[acol + 3][arow] = a.w;
        *(float4*)&Bs[brow][bcol] = b;
        __syncthreads();
        #pragma unroll
        for (int kk = 0; kk < BK; kk++) {
            float4 av = *(const float4*)&As[kk][ty * 4];
            float4 bv = *(const float4*)&Bs[kk][tx * 4];
            acc[0][0] = fmaf(av.x, bv.x, acc[0][0]);
            acc[0][1] = fmaf(av.x, bv.y, acc[0][1]);
            acc[0][2] = fmaf(av.x, bv.z, acc[0][2]);
            acc[0][3] = fmaf(av.x, bv.w, acc[0][3]);
            acc[1][0] = fmaf(av.y, bv.x, acc[1][0]);
            acc[1][1] = fmaf(av.y, bv.y, acc[1][1]);
            acc[1][2] = fmaf(av.y, bv.z, acc[1][2]);
            acc[1][3] = fmaf(av.y, bv.w, acc[1][3]);
            acc[2][0] = fmaf(av.z, bv.x, acc[2][0]);
            acc[2][1] = fmaf(av.z, bv.y, acc[2][1]);
            acc[2][2] = fmaf(av.z, bv.z, acc[2][2]);
            acc[2][3] = fmaf(av.z, bv.w, acc[2][3]);
            acc[3][0] = fmaf(av.w, bv.x, acc[3][0]);
            acc[3][1] = fmaf(av.w, bv.y, acc[3][1]);
            acc[3][2] = fmaf(av.w, bv.z, acc[3][2]);
            acc[3][3] = fmaf(av.w, bv.w, acc[3][3]);
        }
        __syncthreads();
    }

    int row0 = bm0 + ty * 4;
    int col0 = bn0 + tx * 4;
    #pragma unroll
    for (int r = 0; r < 4; r++) {
        if (row0 + r < M) {
            *(float4*)(C + (size_t)(row0 + r) * N + col0) =
                make_float4(acc[r][0], acc[r][1], acc[r][2], acc[r][3]);
        }
    }
}

// ---------------------------------------------------------------------------
// Attention dot products: a_src[n,h] = <h[n,h,:], att_src[h,:]>, same for dst.
// One wave per node.
// ---------------------------------------------------------------------------
template <int HEADS>
__global__ __launch_bounds__(256) void att_dots(const float* __restrict__ h,
                                                const float* __restrict__ att_s,
                                                const float* __restrict__ att_d,
                                                float* __restrict__ a_s,
                                                float* __restrict__ a_d, int n) {
    int wid = (blockIdx.x * blockDim.x + threadIdx.x) >> 6;
    int lane = threadIdx.x & 63;
    if (wid >= n) return;
    const float* row = h + (size_t)wid * 64 * HEADS;
    if (HEADS == 2) {
        float2 v = *(const float2*)(row + lane * 2);
        int head = lane >> 5;
        int ch = (lane * 2) & 63;
        float ps = v.x * att_s[head * 64 + ch] + v.y * att_s[head * 64 + ch + 1];
        float pd = v.x * att_d[head * 64 + ch] + v.y * att_d[head * 64 + ch + 1];
        #pragma unroll
        for (int o = 1; o < 32; o <<= 1) {
            ps += __shfl_xor(ps, o);
            pd += __shfl_xor(pd, o);
        }
        if ((lane & 31) == 0) {
            a_s[wid * 2 + head] = ps;
            a_d[wid * 2 + head] = pd;
        }
    } else {
        float v = row[lane];
        float ps = v * att_s[lane];
        float pd = v * att_d[lane];
        #pragma unroll
        for (int o = 1; o < 64; o <<= 1) {
            ps += __shfl_xor(ps, o);
            pd += __shfl_xor(pd, o);
        }
        if (lane == 0) {
            a_s[wid] = ps;
            a_d[wid] = pd;
        }
    }
}

// ---------------------------------------------------------------------------
// Edge softmax + aggregation, layer 1 (heads=2, 64 ch/head). Wave per dst node.
// Epilogue: +bias, ReLU.
// ---------------------------------------------------------------------------
__global__ __launch_bounds__(256) void edge_agg_l1(
    const int* __restrict__ offs, const int* __restrict__ srcs,
    const float* __restrict__ h1, const float* __restrict__ asv,
    const float* __restrict__ adv, const float* __restrict__ bias,
    float* __restrict__ out, int n) {
    int d = (blockIdx.x * blockDim.x + threadIdx.x) >> 6;
    int lane = threadIdx.x & 63;
    if (d >= n) return;
    int start = offs[d], end = offs[d + 1];
    float ad0 = adv[2 * d], ad1 = adv[2 * d + 1];

    float m0 = -3.4e38f, m1 = -3.4e38f;
    for (int e = start + lane; e < end; e += 64) {
        int s = srcs[e];
        float r0 = asv[2 * s] + ad0;     r0 = r0 < 0.f ? 0.2f * r0 : r0;
        float r1 = asv[2 * s + 1] + ad1; r1 = r1 < 0.f ? 0.2f * r1 : r1;
        m0 = fmaxf(m0, r0);
        m1 = fmaxf(m1, r1);
    }
    #pragma unroll
    for (int o = 1; o < 64; o <<= 1) {
        m0 = fmaxf(m0, __shfl_xor(m0, o));
        m1 = fmaxf(m1, __shfl_xor(m1, o));
    }
    float s0 = 0.f, s1 = 0.f;
    for (int e = start + lane; e < end; e += 64) {
        int s = srcs[e];
        float r0 = asv[2 * s] + ad0;     r0 = r0 < 0.f ? 0.2f * r0 : r0;
        float r1 = asv[2 * s + 1] + ad1; r1 = r1 < 0.f ? 0.2f * r1 : r1;
        s0 += __expf(r0 - m0);
        s1 += __expf(r1 - m1);
    }
    #pragma unroll
    for (int o = 1; o < 64; o <<= 1) {
        s0 += __shfl_xor(s0, o);
        s1 += __shfl_xor(s1, o);
    }
    float inv0 = 1.f / (s0 + 1e-16f), inv1 = 1.f / (s1 + 1e-16f);

    int head = lane >> 5;
    float mh = head ? m1 : m0;
    float invh = head ? inv1 : inv0;
    float adh = head ? ad1 : ad0;
    int c = lane * 2;   // channels c, c+1 (0..127); head = c/64 == lane/32
    float accx = 0.f, accy = 0.f;
    for (int e = start; e < end; ++e) {
        int s = srcs[e];
        float r = asv[2 * s + head] + adh;
        r = r < 0.f ? 0.2f * r : r;
        float w = __expf(r - mh) * invh;
        float2 v = *(const float2*)(h1 + (size_t)s * 128 + c);
        accx = fmaf(w, v.x, accx);
        accy = fmaf(w, v.y, accy);
    }
    accx = fmaxf(accx + bias[c], 0.f);
    accy = fmaxf(accy + bias[c + 1], 0.f);
    *(float2*)(out + (size_t)d * 128 + c) = make_float2(accx, accy);
}

// ---------------------------------------------------------------------------
// Edge softmax + aggregation, layer 2 (heads=1, 64 ch) + bias + log_softmax.
// Wave per dst node; lane = channel.
// ---------------------------------------------------------------------------
__global__ __launch_bounds__(256) void edge_agg_l2(
    const int* __restrict__ offs, const int* __restrict__ srcs,
    const float* __restrict__ h2, const float* __restrict__ asv,
    const float* __restrict__ adv, const float* __restrict__ bias,
    float* __restrict__ out, int n) {
    int d = (blockIdx.x * blockDim.x + threadIdx.x) >> 6;
    int lane = threadIdx.x & 63;
    if (d >= n) return;
    int start = offs[d], end = offs[d + 1];
    float ad = adv[d];

    float m = -3.4e38f;
    for (int e = start + lane; e < end; e += 64) {
        int s = srcs[e];
        float r = asv[s] + ad;
        r = r < 0.f ? 0.2f * r : r;
        m = fmaxf(m, r);
    }
    #pragma unroll
    for (int o = 1; o < 64; o <<= 1) m = fmaxf(m, __shfl_xor(m, o));

    float ssum = 0.f;
    for (int e = start + lane; e < end; e += 64) {
        int s = srcs[e];
        float r = asv[s] + ad;
        r = r < 0.f ? 0.2f * r : r;
        ssum += __expf(r - m);
    }
    #pragma unroll
    for (int o = 1; o < 64; o <<= 1) ssum += __shfl_xor(ssum, o);
    float inv = 1.f / (ssum + 1e-16f);

    float acc = 0.f;
    for (int e = start; e < end; ++e) {
        int s = srcs[e];
        float r = asv[s] + ad;
        r = r < 0.f ? 0.2f * r : r;
        float w = __expf(r - m) * inv;
        acc = fmaf(w, h2[(size_t)s * 64 + lane], acc);
    }
    float v = acc + bias[lane];

    // log_softmax over the 64 channels (= 64 lanes)
    float vm = v;
    #pragma unroll
    for (int o = 1; o < 64; o <<= 1) vm = fmaxf(vm, __shfl_xor(vm, o));
    float ex = __expf(v - vm);
    float se = ex;
    #pragma unroll
    for (int o = 1; o < 64; o <<= 1) se += __shfl_xor(se, o);
    out[(size_t)d * 64 + lane] = v - vm - logf(se);
}

// ---------------------------------------------------------------------------
// Launch
// ---------------------------------------------------------------------------
extern "C" void kernel_launch(void* const* d_in, const int* in_sizes, int n_in,
                              void* d_out, int out_size, void* d_ws, size_t ws_size,
                              hipStream_t stream) {
    const float* x    = (const float*)d_in[0];
    const int*   ei   = (const int*)d_in[1];
    const float* W1   = (const float*)d_in[2];
    const float* as1w = (const float*)d_in[3];
    const float* ad1w = (const float*)d_in[4];
    const float* b1   = (const float*)d_in[5];
    const float* W2   = (const float*)d_in[6];
    const float* as2w = (const float*)d_in[7];
    const float* ad2w = (const float*)d_in[8];
    const float* b2   = (const float*)d_in[9];
    float* out = (float*)d_out;

    const int n = in_sizes[0] / 256;      // 50000
    const int E = in_sizes[1] / 2;        // 1600000
    const int tot = E + n;                // with self loops

    // workspace layout (256B aligned slices)
    char* p = (char*)d_ws;
    auto alloc = [&](size_t bytes) {
        void* r = (void*)p;
        p += (bytes + 255) & ~(size_t)255;
        return r;
    };
    int*   offs    = (int*)alloc((size_t)(n + 1) * 4);
    int*   cursor  = (int*)alloc((size_t)(n + 1) * 4);
    int*   blksums = (int*)alloc(64 * 4);
    int*   srcs    = (int*)alloc((size_t)tot * 4);
    float* h1      = (float*)alloc((size_t)n * 128 * 4);
    float* out1    = (float*)alloc((size_t)n * 128 * 4);
    float* h2      = (float*)alloc((size_t)n * 64 * 4);
    float* a_s1    = (float*)alloc((size_t)n * 2 * 4);
    float* a_d1    = (float*)alloc((size_t)n * 2 * 4);
    float* a_s2    = (float*)alloc((size_t)n * 4);
    float* a_d2    = (float*)alloc((size_t)n * 4);

    int nb = (n + 1023) / 1024;   // scan blocks (49)

    // --- CSR build ---
    init_counts<<<(n + 256) / 256, 256, 0, stream>>>(offs, n);
    hist_kernel<<<(E + 255) / 256, 256, 0, stream>>>(ei, E, offs);
    scan_local<<<nb, 1024, 0, stream>>>(offs, blksums, n);
    scan_blksums<<<1, 64, 0, stream>>>(blksums, nb);
    scan_add<<<nb, 1024, 0, stream>>>(offs, blksums, cursor, n);
    scatter_kernel<<<(tot + 255) / 256, 256, 0, stream>>>(ei, E, n, cursor, srcs);

    // --- Layer 1 ---
    {
        dim3 g((n + BM - 1) / BM, 128 / BN);
        sgemm<<<g, 256, 0, stream>>>(x, W1, h1, n, 256, 128);
    }
    att_dots<2><<<(n * 64 + 255) / 256, 256, 0, stream>>>(h1, as1w, ad1w, a_s1, a_d1, n);
    edge_agg_l1<<<(n * 64 + 255) / 256, 256, 0, stream>>>(offs, srcs, h1, a_s1, a_d1, b1, out1, n);

    // --- Layer 2 ---
    {
        dim3 g((n + BM - 1) / BM, 64 / BN);
        sgemm<<<g, 256, 0, stream>>>(out1, W2, h2, n, 128, 64);
    }
    att_dots<1><<<(n * 64 + 255) / 256, 256, 0, stream>>>(h2, as2w, ad2w, a_s2, a_d2, n);
    edge_agg_l2<<<(n * 64 + 255) / 256, 256, 0, stream>>>(offs, srcs, h2, a_s2, a_d2, b2, out, n);
}

// Round 2
// 517.712 us; speedup vs baseline: 1.4195x; 1.4195x over previous
//
#include <hip/hip_runtime.h>
#include <hip/hip_bf16.h>
#include <math.h>

typedef short bf16x8 __attribute__((ext_vector_type(8)));
typedef float f32x4 __attribute__((ext_vector_type(4)));

// ---------------------------------------------------------------------------
// CSR build: histogram -> scan -> scatter (group edges by dst, incl self-loops)
// ---------------------------------------------------------------------------

__global__ void init_counts(int* __restrict__ offs, int n) {
    int i = blockIdx.x * blockDim.x + threadIdx.x;
    if (i <= n) offs[i] = (i == 0) ? 0 : 1;   // 1 = self-loop per node
}

__global__ void hist_kernel(const int* __restrict__ ei, int E, int* __restrict__ offs) {
    int i = blockIdx.x * blockDim.x + threadIdx.x;
    if (i < E) {
        int d = ei[E + i];          // dst row of edge_index
        atomicAdd(&offs[1 + d], 1);
    }
}

__global__ void scan_local(int* __restrict__ offs, int* __restrict__ blksums, int n) {
    __shared__ int lds[1024];
    int i = 1 + blockIdx.x * 1024 + threadIdx.x;
    int v = (i <= n) ? offs[i] : 0;
    lds[threadIdx.x] = v;
    __syncthreads();
    #pragma unroll
    for (int o = 1; o < 1024; o <<= 1) {
        int t = (threadIdx.x >= o) ? lds[threadIdx.x - o] : 0;
        __syncthreads();
        lds[threadIdx.x] += t;
        __syncthreads();
    }
    if (i <= n) offs[i] = lds[threadIdx.x];
    if (threadIdx.x == 1023) blksums[blockIdx.x] = lds[1023];
}

__global__ void scan_blksums(int* __restrict__ blksums, int nb) {
    int lane = threadIdx.x;   // single wave of 64, nb <= 64
    int v = (lane < nb) ? blksums[lane] : 0;
    #pragma unroll
    for (int o = 1; o < 64; o <<= 1) {
        int t = __shfl_up(v, o);
        if (lane >= o) v += t;
    }
    if (lane < nb) blksums[lane] = v;
}

__global__ void scan_add(int* __restrict__ offs, const int* __restrict__ blksums,
                         int* __restrict__ cursor, int n) {
    int i = 1 + blockIdx.x * 1024 + threadIdx.x;
    if (i > n) return;
    int add = (blockIdx.x > 0) ? blksums[blockIdx.x - 1] : 0;
    int val = offs[i] + add;
    offs[i] = val;
    if (i < n) cursor[i] = val;
    if (i == 1) cursor[0] = 0;
}

__global__ void scatter_kernel(const int* __restrict__ ei, int E, int n,
                               int* __restrict__ cursor, int* __restrict__ srcs) {
    int i = blockIdx.x * blockDim.x + threadIdx.x;
    int total = E + n;
    if (i >= total) return;
    int s, d;
    if (i < E) { s = ei[i]; d = ei[E + i]; }
    else       { s = d = i - E; }            // self loops
    int p = atomicAdd(&cursor[d], 1);
    srcs[p] = s;
}

// ---------------------------------------------------------------------------
// Weight prep: Wt[n][k] = (bf16) W[k][n]
// ---------------------------------------------------------------------------
__global__ void transpose_w(const float* __restrict__ W, __hip_bfloat16* __restrict__ Wt,
                            int K, int N) {
    int idx = blockIdx.x * blockDim.x + threadIdx.x;
    if (idx >= K * N) return;
    int nn = idx / K, kk = idx % K;
    Wt[idx] = __float2bfloat16(W[(size_t)kk * N + nn]);
}

// ---------------------------------------------------------------------------
// MFMA bf16 GEMM: C[M,N](bf16) = A[M,K] @ Bt[N,K]^T
// A fp32 (converted on stage) or bf16. Block 256 = 4 waves, tile 64 x N.
// Fragment layouts (m89/m91-verified):
//   a_frag: A[m = lane&15][k = (lane>>4)*8 + j]
//   b_frag: B[k = (lane>>4)*8 + j][n = lane&15]  (read from Bt[n][k])
//   d_frag: D[row = (lane>>4)*4 + r][col = lane&15]
// ---------------------------------------------------------------------------
template <bool A_BF16, int NT>
__global__ __launch_bounds__(256) void gemm_mfma(
    const void* __restrict__ Av, const __hip_bfloat16* __restrict__ Bt,
    __hip_bfloat16* __restrict__ C, int M, int K) {
    constexpr int N = NT * 16;
    __shared__ __hip_bfloat16 As[64][40];   // row stride 80 B (16B-aligned, low conflict)
    int tid = threadIdx.x;
    int w = tid >> 6, l = tid & 63;
    int q = l >> 4, m16 = l & 15;
    int bm = blockIdx.x * 64;

    int lr = tid >> 2, lseg = tid & 3;       // loader: row, 8-col segment
    int arow = bm + lr; if (arow >= M) arow = M - 1;

    f32x4 acc[NT];
    #pragma unroll
    for (int t = 0; t < NT; t++) acc[t] = (f32x4){0.f, 0.f, 0.f, 0.f};

    for (int kc = 0; kc < K; kc += 32) {
        if (A_BF16) {
            const __hip_bfloat16* A = (const __hip_bfloat16*)Av;
            uint4 v = *(const uint4*)(A + (size_t)arow * K + kc + lseg * 8);
            *(uint4*)&As[lr][lseg * 8] = v;
        } else {
            const float* A = (const float*)Av;
            float4 v0 = *(const float4*)(A + (size_t)arow * K + kc + lseg * 8);
            float4 v1 = *(const float4*)(A + (size_t)arow * K + kc + lseg * 8 + 4);
            union { __hip_bfloat16 h[8]; uint4 u; } tmp;
            tmp.h[0] = __float2bfloat16(v0.x); tmp.h[1] = __float2bfloat16(v0.y);
            tmp.h[2] = __float2bfloat16(v0.z); tmp.h[3] = __float2bfloat16(v0.w);
            tmp.h[4] = __float2bfloat16(v1.x); tmp.h[5] = __float2bfloat16(v1.y);
            tmp.h[6] = __float2bfloat16(v1.z); tmp.h[7] = __float2bfloat16(v1.w);
            *(uint4*)&As[lr][lseg * 8] = tmp.u;
        }
        __syncthreads();
        bf16x8 a = *(const bf16x8*)&As[w * 16 + m16][q * 8];
        #pragma unroll
        for (int t = 0; t < NT; t++) {
            bf16x8 b = *(const bf16x8*)(Bt + (size_t)(t * 16 + m16) * K + kc + q * 8);
            acc[t] = __builtin_amdgcn_mfma_f32_16x16x32_bf16(a, b, acc[t], 0, 0, 0);
        }
        __syncthreads();
    }

    #pragma unroll
    for (int t = 0; t < NT; t++) {
        #pragma unroll
        for (int r = 0; r < 4; r++) {
            int row = bm + w * 16 + q * 4 + r;
            if (row < M) C[(size_t)row * N + t * 16 + m16] = __float2bfloat16(acc[t][r]);
        }
    }
}

// ---------------------------------------------------------------------------
// Attention dot products from bf16 h. One wave per node.
// ---------------------------------------------------------------------------
template <int HEADS>
__global__ __launch_bounds__(256) void att_dots(const __hip_bfloat16* __restrict__ h,
                                                const float* __restrict__ att_s,
                                                const float* __restrict__ att_d,
                                                float* __restrict__ a_s,
                                                float* __restrict__ a_d, int n) {
    int wid = (blockIdx.x * blockDim.x + threadIdx.x) >> 6;
    int lane = threadIdx.x & 63;
    if (wid >= n) return;
    const __hip_bfloat16* row = h + (size_t)wid * 64 * HEADS;
    if (HEADS == 2) {
        __hip_bfloat162 v = *(const __hip_bfloat162*)(row + lane * 2);
        float vx = __bfloat162float(v.x), vy = __bfloat162float(v.y);
        int head = lane >> 5;
        int ch = (lane * 2) & 63;
        float ps = vx * att_s[head * 64 + ch] + vy * att_s[head * 64 + ch + 1];
        float pd = vx * att_d[head * 64 + ch] + vy * att_d[head * 64 + ch + 1];
        #pragma unroll
        for (int o = 1; o < 32; o <<= 1) {
            ps += __shfl_xor(ps, o);
            pd += __shfl_xor(pd, o);
        }
        if ((lane & 31) == 0) {
            a_s[wid * 2 + head] = ps;
            a_d[wid * 2 + head] = pd;
        }
    } else {
        float v = __bfloat162float(row[lane]);
        float ps = v * att_s[lane];
        float pd = v * att_d[lane];
        #pragma unroll
        for (int o = 1; o < 64; o <<= 1) {
            ps += __shfl_xor(ps, o);
            pd += __shfl_xor(pd, o);
        }
        if (lane == 0) {
            a_s[wid] = ps;
            a_d[wid] = pd;
        }
    }
}

__device__ __forceinline__ float leaky(float r) {
    return r < 0.f ? 0.2f * r : r;
}

// ---------------------------------------------------------------------------
// Edge softmax + aggregation, layer 1 (heads=2). Wave per dst node.
// Pass 1: online max+sum. Pass 2: 4x-unrolled weighted gather (bf16 h1).
// Epilogue: +bias, ReLU, bf16 store.
// ---------------------------------------------------------------------------
__global__ __launch_bounds__(256) void edge_agg_l1(
    const int* __restrict__ offs, const int* __restrict__ srcs,
    const __hip_bfloat16* __restrict__ h1, const float* __restrict__ asv,
    const float* __restrict__ adv, const float* __restrict__ bias,
    __hip_bfloat16* __restrict__ out, int n) {
    int d = (blockIdx.x * blockDim.x + threadIdx.x) >> 6;
    int lane = threadIdx.x & 63;
    if (d >= n) return;
    int start = offs[d], end = offs[d + 1];
    float ad0 = adv[2 * d], ad1 = adv[2 * d + 1];

    // pass 1: per-lane online softmax stats
    float m0 = -3.4e38f, m1 = -3.4e38f, s0 = 0.f, s1 = 0.f;
    for (int e = start + lane; e < end; e += 64) {
        int s = srcs[e];
        float2 a = *(const float2*)(asv + 2 * s);
        float r0 = leaky(a.x + ad0);
        float r1 = leaky(a.y + ad1);
        if (r0 > m0) { s0 *= __expf(m0 - r0); m0 = r0; }
        s0 += __expf(r0 - m0);
        if (r1 > m1) { s1 *= __expf(m1 - r1); m1 = r1; }
        s1 += __expf(r1 - m1);
    }
    #pragma unroll
    for (int o = 1; o < 64; o <<= 1) {
        float om0 = __shfl_xor(m0, o), os0 = __shfl_xor(s0, o);
        float nm0 = fmaxf(m0, om0);
        s0 = s0 * __expf(m0 - nm0) + os0 * __expf(om0 - nm0);
        m0 = nm0;
        float om1 = __shfl_xor(m1, o), os1 = __shfl_xor(s1, o);
        float nm1 = fmaxf(m1, om1);
        s1 = s1 * __expf(m1 - nm1) + os1 * __expf(om1 - nm1);
        m1 = nm1;
    }
    float inv0 = 1.f / (s0 + 1e-16f), inv1 = 1.f / (s1 + 1e-16f);

    int head = lane >> 5;
    float mh = head ? m1 : m0;
    float invh = head ? inv1 : inv0;
    float adh = head ? ad1 : ad0;
    int c = lane * 2;   // channels c, c+1 (0..127)
    float ax0 = 0.f, ay0 = 0.f, ax1 = 0.f, ay1 = 0.f;
    int e = start;
    for (; e + 4 <= end; e += 4) {
        int sA = srcs[e], sB = srcs[e + 1], sC = srcs[e + 2], sD = srcs[e + 3];
        float wA = __expf(leaky(asv[2 * sA + head] + adh) - mh) * invh;
        float wB = __expf(leaky(asv[2 * sB + head] + adh) - mh) * invh;
        float wC = __expf(leaky(asv[2 * sC + head] + adh) - mh) * invh;
        float wD = __expf(leaky(asv[2 * sD + head] + adh) - mh) * invh;
        __hip_bfloat162 vA = *(const __hip_bfloat162*)(h1 + (size_t)sA * 128 + c);
        __hip_bfloat162 vB = *(const __hip_bfloat162*)(h1 + (size_t)sB * 128 + c);
        __hip_bfloat162 vC = *(const __hip_bfloat162*)(h1 + (size_t)sC * 128 + c);
        __hip_bfloat162 vD = *(const __hip_bfloat162*)(h1 + (size_t)sD * 128 + c);
        ax0 = fmaf(wA, __bfloat162float(vA.x), ax0);
        ay0 = fmaf(wA, __bfloat162float(vA.y), ay0);
        ax1 = fmaf(wB, __bfloat162float(vB.x), ax1);
        ay1 = fmaf(wB, __bfloat162float(vB.y), ay1);
        ax0 = fmaf(wC, __bfloat162float(vC.x), ax0);
        ay0 = fmaf(wC, __bfloat162float(vC.y), ay0);
        ax1 = fmaf(wD, __bfloat162float(vD.x), ax1);
        ay1 = fmaf(wD, __bfloat162float(vD.y), ay1);
    }
    for (; e < end; ++e) {
        int s = srcs[e];
        float w = __expf(leaky(asv[2 * s + head] + adh) - mh) * invh;
        __hip_bfloat162 v = *(const __hip_bfloat162*)(h1 + (size_t)s * 128 + c);
        ax0 = fmaf(w, __bfloat162float(v.x), ax0);
        ay0 = fmaf(w, __bfloat162float(v.y), ay0);
    }
    float ox = fmaxf(ax0 + ax1 + bias[c], 0.f);
    float oy = fmaxf(ay0 + ay1 + bias[c + 1], 0.f);
    __hip_bfloat162 o2;
    o2.x = __float2bfloat16(ox);
    o2.y = __float2bfloat16(oy);
    *(__hip_bfloat162*)(out + (size_t)d * 128 + c) = o2;
}

// ---------------------------------------------------------------------------
// Edge softmax + aggregation, layer 2 (heads=1) + bias + log_softmax.
// Wave per dst node; lane = channel.
// ---------------------------------------------------------------------------
__global__ __launch_bounds__(256) void edge_agg_l2(
    const int* __restrict__ offs, const int* __restrict__ srcs,
    const __hip_bfloat16* __restrict__ h2, const float* __restrict__ asv,
    const float* __restrict__ adv, const float* __restrict__ bias,
    float* __restrict__ out, int n) {
    int d = (blockIdx.x * blockDim.x + threadIdx.x) >> 6;
    int lane = threadIdx.x & 63;
    if (d >= n) return;
    int start = offs[d], end = offs[d + 1];
    float ad = adv[d];

    float m = -3.4e38f, ssum = 0.f;
    for (int e = start + lane; e < end; e += 64) {
        int s = srcs[e];
        float r = leaky(asv[s] + ad);
        if (r > m) { ssum *= __expf(m - r); m = r; }
        ssum += __expf(r - m);
    }
    #pragma unroll
    for (int o = 1; o < 64; o <<= 1) {
        float om = __shfl_xor(m, o), os = __shfl_xor(ssum, o);
        float nm = fmaxf(m, om);
        ssum = ssum * __expf(m - nm) + os * __expf(om - nm);
        m = nm;
    }
    float inv = 1.f / (ssum + 1e-16f);

    float a0 = 0.f, a1 = 0.f;
    int e = start;
    for (; e + 4 <= end; e += 4) {
        int sA = srcs[e], sB = srcs[e + 1], sC = srcs[e + 2], sD = srcs[e + 3];
        float wA = __expf(leaky(asv[sA] + ad) - m) * inv;
        float wB = __expf(leaky(asv[sB] + ad) - m) * inv;
        float wC = __expf(leaky(asv[sC] + ad) - m) * inv;
        float wD = __expf(leaky(asv[sD] + ad) - m) * inv;
        float vA = __bfloat162float(h2[(size_t)sA * 64 + lane]);
        float vB = __bfloat162float(h2[(size_t)sB * 64 + lane]);
        float vC = __bfloat162float(h2[(size_t)sC * 64 + lane]);
        float vD = __bfloat162float(h2[(size_t)sD * 64 + lane]);
        a0 = fmaf(wA, vA, a0);
        a1 = fmaf(wB, vB, a1);
        a0 = fmaf(wC, vC, a0);
        a1 = fmaf(wD, vD, a1);
    }
    for (; e < end; ++e) {
        int s = srcs[e];
        float w = __expf(leaky(asv[s] + ad) - m) * inv;
        a0 = fmaf(w, __bfloat162float(h2[(size_t)s * 64 + lane]), a0);
    }
    float v = a0 + a1 + bias[lane];

    // log_softmax over the 64 channels (= 64 lanes)
    float vm = v;
    #pragma unroll
    for (int o = 1; o < 64; o <<= 1) vm = fmaxf(vm, __shfl_xor(vm, o));
    float ex = __expf(v - vm);
    float se = ex;
    #pragma unroll
    for (int o = 1; o < 64; o <<= 1) se += __shfl_xor(se, o);
    out[(size_t)d * 64 + lane] = v - vm - logf(se);
}

// ---------------------------------------------------------------------------
// Launch
// ---------------------------------------------------------------------------
extern "C" void kernel_launch(void* const* d_in, const int* in_sizes, int n_in,
                              void* d_out, int out_size, void* d_ws, size_t ws_size,
                              hipStream_t stream) {
    const float* x    = (const float*)d_in[0];
    const int*   ei   = (const int*)d_in[1];
    const float* W1   = (const float*)d_in[2];
    const float* as1w = (const float*)d_in[3];
    const float* ad1w = (const float*)d_in[4];
    const float* b1   = (const float*)d_in[5];
    const float* W2   = (const float*)d_in[6];
    const float* as2w = (const float*)d_in[7];
    const float* ad2w = (const float*)d_in[8];
    const float* b2   = (const float*)d_in[9];
    float* out = (float*)d_out;

    const int n = in_sizes[0] / 256;      // 50000
    const int E = in_sizes[1] / 2;        // 1600000
    const int tot = E + n;                // with self loops

    char* p = (char*)d_ws;
    auto alloc = [&](size_t bytes) {
        void* r = (void*)p;
        p += (bytes + 255) & ~(size_t)255;
        return r;
    };
    int*   offs    = (int*)alloc((size_t)(n + 1) * 4);
    int*   cursor  = (int*)alloc((size_t)(n + 1) * 4);
    int*   blksums = (int*)alloc(64 * 4);
    int*   srcs    = (int*)alloc((size_t)tot * 4);
    __hip_bfloat16* W1t = (__hip_bfloat16*)alloc((size_t)128 * 256 * 2);
    __hip_bfloat16* W2t = (__hip_bfloat16*)alloc((size_t)64 * 128 * 2);
    __hip_bfloat16* h1  = (__hip_bfloat16*)alloc((size_t)n * 128 * 2);
    __hip_bfloat16* out1= (__hip_bfloat16*)alloc((size_t)n * 128 * 2);
    __hip_bfloat16* h2  = (__hip_bfloat16*)alloc((size_t)n * 64 * 2);
    float* a_s1 = (float*)alloc((size_t)n * 2 * 4);
    float* a_d1 = (float*)alloc((size_t)n * 2 * 4);
    float* a_s2 = (float*)alloc((size_t)n * 4);
    float* a_d2 = (float*)alloc((size_t)n * 4);

    int nb = (n + 1023) / 1024;

    // --- CSR build ---
    init_counts<<<(n + 256) / 256, 256, 0, stream>>>(offs, n);
    hist_kernel<<<(E + 255) / 256, 256, 0, stream>>>(ei, E, offs);
    scan_local<<<nb, 1024, 0, stream>>>(offs, blksums, n);
    scan_blksums<<<1, 64, 0, stream>>>(blksums, nb);
    scan_add<<<nb, 1024, 0, stream>>>(offs, blksums, cursor, n);
    scatter_kernel<<<(tot + 255) / 256, 256, 0, stream>>>(ei, E, n, cursor, srcs);

    // --- weight prep ---
    transpose_w<<<(128 * 256 + 255) / 256, 256, 0, stream>>>(W1, W1t, 256, 128);
    transpose_w<<<(64 * 128 + 255) / 256, 256, 0, stream>>>(W2, W2t, 128, 64);

    // --- Layer 1 ---
    gemm_mfma<false, 8><<<(n + 63) / 64, 256, 0, stream>>>(x, W1t, h1, n, 256);
    att_dots<2><<<(n * 64 + 255) / 256, 256, 0, stream>>>(h1, as1w, ad1w, a_s1, a_d1, n);
    edge_agg_l1<<<(n * 64 + 255) / 256, 256, 0, stream>>>(offs, srcs, h1, a_s1, a_d1, b1, out1, n);

    // --- Layer 2 ---
    gemm_mfma<true, 4><<<(n + 63) / 64, 256, 0, stream>>>(out1, W2t, h2, n, 128);
    att_dots<1><<<(n * 64 + 255) / 256, 256, 0, stream>>>(h2, as2w, ad2w, a_s2, a_d2, n);
    edge_agg_l2<<<(n * 64 + 255) / 256, 256, 0, stream>>>(offs, srcs, h2, a_s2, a_d2, b2, out, n);
}

// Round 3
// 370.447 us; speedup vs baseline: 1.9839x; 1.3975x over previous
//
#include <hip/hip_runtime.h>
#include <hip/hip_bf16.h>
#include <math.h>

typedef short bf16x8 __attribute__((ext_vector_type(8)));
typedef float f32x4 __attribute__((ext_vector_type(4)));

#define BSHIFT 7
#define BWIDTH 128      // nodes per bucket
#define PCHUNK 4096     // edges per partition block

// ---------------------------------------------------------------------------
// Bucketed CSR build (group edges by dst, self-loops appended analytically)
// ---------------------------------------------------------------------------

__global__ void zero_buf(int* __restrict__ p, int n) {
    int i = blockIdx.x * blockDim.x + threadIdx.x;
    if (i < n) p[i] = 0;
}

// per-block LDS histogram of dst buckets
__global__ __launch_bounds__(256) void bucket_hist(const int* __restrict__ ei, int E,
                                                   int* __restrict__ bcnt) {
    __shared__ int h[512];
    int tid = threadIdx.x;
    for (int i = tid; i < 512; i += 256) h[i] = 0;
    __syncthreads();
    int start = blockIdx.x * PCHUNK;
    int cnt = min(PCHUNK, E - start);
    for (int i = tid; i < cnt; i += 256)
        atomicAdd(&h[ei[E + start + i] >> BSHIFT], 1);
    __syncthreads();
    for (int i = tid; i < 512; i += 256)
        if (h[i]) atomicAdd(&bcnt[i], h[i]);
}

// single-block scan over bucket counts (+nodes per bucket for self-loops)
__global__ __launch_bounds__(512) void bucket_scan(const int* __restrict__ bcnt,
                                                   int* __restrict__ bbase,
                                                   int* __restrict__ bcur,
                                                   int nbk, int n) {
    __shared__ int s[512];
    int tid = threadIdx.x;
    int nodes = 0;
    if (tid < nbk) nodes = min(BWIDTH, n - (tid << BSHIFT));
    int v = (tid < nbk) ? bcnt[tid] + nodes : 0;
    s[tid] = v;
    __syncthreads();
    #pragma unroll
    for (int o = 1; o < 512; o <<= 1) {
        int t = (tid >= o) ? s[tid - o] : 0;
        __syncthreads();
        s[tid] += t;
        __syncthreads();
    }
    if (tid < nbk) {
        int ex = s[tid] - v;
        bbase[tid] = ex;
        bcur[tid] = ex - (tid << BSHIFT);   // tmp-space cursor (edges only)
    }
    if (tid == nbk) bbase[nbk] = s[tid];    // total = E + n
}

// partition edges into bucket-contiguous tmp[] as (src,dst) pairs
__global__ __launch_bounds__(256) void partition_edges(const int* __restrict__ ei, int E,
                                                       int* __restrict__ bcur,
                                                       int2* __restrict__ tmp) {
    __shared__ int2 stage[PCHUNK];
    __shared__ int h[512];
    __shared__ int lbase[512];
    int tid = threadIdx.x;
    int start = blockIdx.x * PCHUNK;
    int cnt = min(PCHUNK, E - start);
    for (int i = tid; i < 512; i += 256) h[i] = 0;
    __syncthreads();
    for (int i = tid; i < cnt; i += 256) {
        int s = ei[start + i];
        int d = ei[E + start + i];
        stage[i] = make_int2(s, d);
        atomicAdd(&h[d >> BSHIFT], 1);
    }
    __syncthreads();
    for (int i = tid; i < 512; i += 256) {
        if (h[i] > 0) lbase[i] = atomicAdd(&bcur[i], h[i]);
        h[i] = 0;
    }
    __syncthreads();
    for (int i = tid; i < cnt; i += 256) {
        int2 e = stage[i];
        int b = e.y >> BSHIFT;
        int r = atomicAdd(&h[b], 1);
        tmp[lbase[b] + r] = e;
    }
}

// one block per bucket: local counts -> local scan -> offs + srcs
__global__ __launch_bounds__(256) void bucket_csr(const int* __restrict__ bbase,
                                                  const int2* __restrict__ tmp,
                                                  int* __restrict__ offs,
                                                  int* __restrict__ srcs,
                                                  int n, int nbk) {
    __shared__ int cnt[BWIDTH];
    __shared__ int sa[BWIDTH];
    __shared__ int cur[BWIDTH];
    int b = blockIdx.x;
    int tid = threadIdx.x;
    int node0 = b << BSHIFT;
    int nnodes = min(BWIDTH, n - node0);
    int cb = bbase[b];
    int ce = bbase[b + 1];
    int tb = cb - node0;                 // tmp base (node0 == b*128 self-loops before)
    int ecnt = (ce - cb) - nnodes;       // real edges in this bucket

    if (tid < BWIDTH) cnt[tid] = (tid < nnodes) ? 1 : 0;   // self-loop seed
    __syncthreads();
    for (int i = tid; i < ecnt; i += 256)
        atomicAdd(&cnt[tmp[tb + i].y & (BWIDTH - 1)], 1);
    __syncthreads();
    if (tid < BWIDTH) sa[tid] = cnt[tid];
    __syncthreads();
    #pragma unroll
    for (int o = 1; o < BWIDTH; o <<= 1) {
        int v = 0;
        if (tid < BWIDTH) { v = sa[tid]; if (tid >= o) v += sa[tid - o]; }
        __syncthreads();
        if (tid < BWIDTH) sa[tid] = v;
        __syncthreads();
    }
    if (tid < BWIDTH) {
        int ex = sa[tid] - cnt[tid];     // exclusive local offset
        if (tid < nnodes) {
            offs[node0 + tid] = cb + ex;
            srcs[cb + ex] = node0 + tid; // self-loop first in segment
        }
        cur[tid] = ex + (tid < nnodes ? 1 : 0);
    }
    if (b == nbk - 1 && tid == 0) offs[n] = ce;
    __syncthreads();
    for (int i = tid; i < ecnt; i += 256) {
        int2 e = tmp[tb + i];
        int li = e.y & (BWIDTH - 1);
        int r = atomicAdd(&cur[li], 1);
        srcs[cb + r] = e.x;
    }
}

// ---------------------------------------------------------------------------
// Weight prep: Wt[n][k] = (bf16) W[k][n]
// ---------------------------------------------------------------------------
__global__ void transpose_w(const float* __restrict__ W, __hip_bfloat16* __restrict__ Wt,
                            int K, int N) {
    int idx = blockIdx.x * blockDim.x + threadIdx.x;
    if (idx >= K * N) return;
    int nn = idx / K, kk = idx % K;
    Wt[idx] = __float2bfloat16(W[(size_t)kk * N + nn]);
}

// ---------------------------------------------------------------------------
// MFMA bf16 GEMM: C[M,N](bf16) = A[M,K] @ Bt[N,K]^T
// ---------------------------------------------------------------------------
template <bool A_BF16, int NT>
__global__ __launch_bounds__(256) void gemm_mfma(
    const void* __restrict__ Av, const __hip_bfloat16* __restrict__ Bt,
    __hip_bfloat16* __restrict__ C, int M, int K) {
    constexpr int N = NT * 16;
    __shared__ __hip_bfloat16 As[64][40];
    int tid = threadIdx.x;
    int w = tid >> 6, l = tid & 63;
    int q = l >> 4, m16 = l & 15;
    int bm = blockIdx.x * 64;

    int lr = tid >> 2, lseg = tid & 3;
    int arow = bm + lr; if (arow >= M) arow = M - 1;

    f32x4 acc[NT];
    #pragma unroll
    for (int t = 0; t < NT; t++) acc[t] = (f32x4){0.f, 0.f, 0.f, 0.f};

    for (int kc = 0; kc < K; kc += 32) {
        if (A_BF16) {
            const __hip_bfloat16* A = (const __hip_bfloat16*)Av;
            uint4 v = *(const uint4*)(A + (size_t)arow * K + kc + lseg * 8);
            *(uint4*)&As[lr][lseg * 8] = v;
        } else {
            const float* A = (const float*)Av;
            float4 v0 = *(const float4*)(A + (size_t)arow * K + kc + lseg * 8);
            float4 v1 = *(const float4*)(A + (size_t)arow * K + kc + lseg * 8 + 4);
            union { __hip_bfloat16 h[8]; uint4 u; } tmp;
            tmp.h[0] = __float2bfloat16(v0.x); tmp.h[1] = __float2bfloat16(v0.y);
            tmp.h[2] = __float2bfloat16(v0.z); tmp.h[3] = __float2bfloat16(v0.w);
            tmp.h[4] = __float2bfloat16(v1.x); tmp.h[5] = __float2bfloat16(v1.y);
            tmp.h[6] = __float2bfloat16(v1.z); tmp.h[7] = __float2bfloat16(v1.w);
            *(uint4*)&As[lr][lseg * 8] = tmp.u;
        }
        __syncthreads();
        bf16x8 a = *(const bf16x8*)&As[w * 16 + m16][q * 8];
        #pragma unroll
        for (int t = 0; t < NT; t++) {
            bf16x8 b = *(const bf16x8*)(Bt + (size_t)(t * 16 + m16) * K + kc + q * 8);
            acc[t] = __builtin_amdgcn_mfma_f32_16x16x32_bf16(a, b, acc[t], 0, 0, 0);
        }
        __syncthreads();
    }

    #pragma unroll
    for (int t = 0; t < NT; t++) {
        #pragma unroll
        for (int r = 0; r < 4; r++) {
            int row = bm + w * 16 + q * 4 + r;
            if (row < M) C[(size_t)row * N + t * 16 + m16] = __float2bfloat16(acc[t][r]);
        }
    }
}

// ---------------------------------------------------------------------------
// Attention dot products from bf16 h. One wave per node.
// ---------------------------------------------------------------------------
template <int HEADS>
__global__ __launch_bounds__(256) void att_dots(const __hip_bfloat16* __restrict__ h,
                                                const float* __restrict__ att_s,
                                                const float* __restrict__ att_d,
                                                float* __restrict__ a_s,
                                                float* __restrict__ a_d, int n) {
    int wid = (blockIdx.x * blockDim.x + threadIdx.x) >> 6;
    int lane = threadIdx.x & 63;
    if (wid >= n) return;
    const __hip_bfloat16* row = h + (size_t)wid * 64 * HEADS;
    if (HEADS == 2) {
        __hip_bfloat162 v = *(const __hip_bfloat162*)(row + lane * 2);
        float vx = __bfloat162float(v.x), vy = __bfloat162float(v.y);
        int head = lane >> 5;
        int ch = (lane * 2) & 63;
        float ps = vx * att_s[head * 64 + ch] + vy * att_s[head * 64 + ch + 1];
        float pd = vx * att_d[head * 64 + ch] + vy * att_d[head * 64 + ch + 1];
        #pragma unroll
        for (int o = 1; o < 32; o <<= 1) {
            ps += __shfl_xor(ps, o);
            pd += __shfl_xor(pd, o);
        }
        if ((lane & 31) == 0) {
            a_s[wid * 2 + head] = ps;
            a_d[wid * 2 + head] = pd;
        }
    } else {
        float v = __bfloat162float(row[lane]);
        float ps = v * att_s[lane];
        float pd = v * att_d[lane];
        #pragma unroll
        for (int o = 1; o < 64; o <<= 1) {
            ps += __shfl_xor(ps, o);
            pd += __shfl_xor(pd, o);
        }
        if (lane == 0) {
            a_s[wid] = ps;
            a_d[wid] = pd;
        }
    }
}

__device__ __forceinline__ float leaky(float r) {
    return r < 0.f ? 0.2f * r : r;
}

// ---------------------------------------------------------------------------
// Edge softmax + aggregation, layer 1 (heads=2). Wave per dst node.
// ---------------------------------------------------------------------------
__global__ __launch_bounds__(256) void edge_agg_l1(
    const int* __restrict__ offs, const int* __restrict__ srcs,
    const __hip_bfloat16* __restrict__ h1, const float* __restrict__ asv,
    const float* __restrict__ adv, const float* __restrict__ bias,
    __hip_bfloat16* __restrict__ out, int n) {
    int d = (blockIdx.x * blockDim.x + threadIdx.x) >> 6;
    int lane = threadIdx.x & 63;
    if (d >= n) return;
    int start = offs[d], end = offs[d + 1];
    float ad0 = adv[2 * d], ad1 = adv[2 * d + 1];

    float m0 = -3.4e38f, m1 = -3.4e38f, s0 = 0.f, s1 = 0.f;
    for (int e = start + lane; e < end; e += 64) {
        int s = srcs[e];
        float2 a = *(const float2*)(asv + 2 * s);
        float r0 = leaky(a.x + ad0);
        float r1 = leaky(a.y + ad1);
        if (r0 > m0) { s0 *= __expf(m0 - r0); m0 = r0; }
        s0 += __expf(r0 - m0);
        if (r1 > m1) { s1 *= __expf(m1 - r1); m1 = r1; }
        s1 += __expf(r1 - m1);
    }
    #pragma unroll
    for (int o = 1; o < 64; o <<= 1) {
        float om0 = __shfl_xor(m0, o), os0 = __shfl_xor(s0, o);
        float nm0 = fmaxf(m0, om0);
        s0 = s0 * __expf(m0 - nm0) + os0 * __expf(om0 - nm0);
        m0 = nm0;
        float om1 = __shfl_xor(m1, o), os1 = __shfl_xor(s1, o);
        float nm1 = fmaxf(m1, om1);
        s1 = s1 * __expf(m1 - nm1) + os1 * __expf(om1 - nm1);
        m1 = nm1;
    }
    float inv0 = 1.f / (s0 + 1e-16f), inv1 = 1.f / (s1 + 1e-16f);

    int head = lane >> 5;
    float mh = head ? m1 : m0;
    float invh = head ? inv1 : inv0;
    float adh = head ? ad1 : ad0;
    int c = lane * 2;
    float ax0 = 0.f, ay0 = 0.f, ax1 = 0.f, ay1 = 0.f;
    int e = start;
    for (; e + 4 <= end; e += 4) {
        int sA = srcs[e], sB = srcs[e + 1], sC = srcs[e + 2], sD = srcs[e + 3];
        float wA = __expf(leaky(asv[2 * sA + head] + adh) - mh) * invh;
        float wB = __expf(leaky(asv[2 * sB + head] + adh) - mh) * invh;
        float wC = __expf(leaky(asv[2 * sC + head] + adh) - mh) * invh;
        float wD = __expf(leaky(asv[2 * sD + head] + adh) - mh) * invh;
        __hip_bfloat162 vA = *(const __hip_bfloat162*)(h1 + (size_t)sA * 128 + c);
        __hip_bfloat162 vB = *(const __hip_bfloat162*)(h1 + (size_t)sB * 128 + c);
        __hip_bfloat162 vC = *(const __hip_bfloat162*)(h1 + (size_t)sC * 128 + c);
        __hip_bfloat162 vD = *(const __hip_bfloat162*)(h1 + (size_t)sD * 128 + c);
        ax0 = fmaf(wA, __bfloat162float(vA.x), ax0);
        ay0 = fmaf(wA, __bfloat162float(vA.y), ay0);
        ax1 = fmaf(wB, __bfloat162float(vB.x), ax1);
        ay1 = fmaf(wB, __bfloat162float(vB.y), ay1);
        ax0 = fmaf(wC, __bfloat162float(vC.x), ax0);
        ay0 = fmaf(wC, __bfloat162float(vC.y), ay0);
        ax1 = fmaf(wD, __bfloat162float(vD.x), ax1);
        ay1 = fmaf(wD, __bfloat162float(vD.y), ay1);
    }
    for (; e < end; ++e) {
        int s = srcs[e];
        float w = __expf(leaky(asv[2 * s + head] + adh) - mh) * invh;
        __hip_bfloat162 v = *(const __hip_bfloat162*)(h1 + (size_t)s * 128 + c);
        ax0 = fmaf(w, __bfloat162float(v.x), ax0);
        ay0 = fmaf(w, __bfloat162float(v.y), ay0);
    }
    float ox = fmaxf(ax0 + ax1 + bias[c], 0.f);
    float oy = fmaxf(ay0 + ay1 + bias[c + 1], 0.f);
    __hip_bfloat162 o2;
    o2.x = __float2bfloat16(ox);
    o2.y = __float2bfloat16(oy);
    *(__hip_bfloat162*)(out + (size_t)d * 128 + c) = o2;
}

// ---------------------------------------------------------------------------
// Edge softmax + aggregation, layer 2 (heads=1) + bias + log_softmax.
// ---------------------------------------------------------------------------
__global__ __launch_bounds__(256) void edge_agg_l2(
    const int* __restrict__ offs, const int* __restrict__ srcs,
    const __hip_bfloat16* __restrict__ h2, const float* __restrict__ asv,
    const float* __restrict__ adv, const float* __restrict__ bias,
    float* __restrict__ out, int n) {
    int d = (blockIdx.x * blockDim.x + threadIdx.x) >> 6;
    int lane = threadIdx.x & 63;
    if (d >= n) return;
    int start = offs[d], end = offs[d + 1];
    float ad = adv[d];

    float m = -3.4e38f, ssum = 0.f;
    for (int e = start + lane; e < end; e += 64) {
        int s = srcs[e];
        float r = leaky(asv[s] + ad);
        if (r > m) { ssum *= __expf(m - r); m = r; }
        ssum += __expf(r - m);
    }
    #pragma unroll
    for (int o = 1; o < 64; o <<= 1) {
        float om = __shfl_xor(m, o), os = __shfl_xor(ssum, o);
        float nm = fmaxf(m, om);
        ssum = ssum * __expf(m - nm) + os * __expf(om - nm);
        m = nm;
    }
    float inv = 1.f / (ssum + 1e-16f);

    float a0 = 0.f, a1 = 0.f;
    int e = start;
    for (; e + 4 <= end; e += 4) {
        int sA = srcs[e], sB = srcs[e + 1], sC = srcs[e + 2], sD = srcs[e + 3];
        float wA = __expf(leaky(asv[sA] + ad) - m) * inv;
        float wB = __expf(leaky(asv[sB] + ad) - m) * inv;
        float wC = __expf(leaky(asv[sC] + ad) - m) * inv;
        float wD = __expf(leaky(asv[sD] + ad) - m) * inv;
        float vA = __bfloat162float(h2[(size_t)sA * 64 + lane]);
        float vB = __bfloat162float(h2[(size_t)sB * 64 + lane]);
        float vC = __bfloat162float(h2[(size_t)sC * 64 + lane]);
        float vD = __bfloat162float(h2[(size_t)sD * 64 + lane]);
        a0 = fmaf(wA, vA, a0);
        a1 = fmaf(wB, vB, a1);
        a0 = fmaf(wC, vC, a0);
        a1 = fmaf(wD, vD, a1);
    }
    for (; e < end; ++e) {
        int s = srcs[e];
        float w = __expf(leaky(asv[s] + ad) - m) * inv;
        a0 = fmaf(w, __bfloat162float(h2[(size_t)s * 64 + lane]), a0);
    }
    float v = a0 + a1 + bias[lane];

    float vm = v;
    #pragma unroll
    for (int o = 1; o < 64; o <<= 1) vm = fmaxf(vm, __shfl_xor(vm, o));
    float ex = __expf(v - vm);
    float se = ex;
    #pragma unroll
    for (int o = 1; o < 64; o <<= 1) se += __shfl_xor(se, o);
    out[(size_t)d * 64 + lane] = v - vm - logf(se);
}

// ---------------------------------------------------------------------------
// Launch
// ---------------------------------------------------------------------------
extern "C" void kernel_launch(void* const* d_in, const int* in_sizes, int n_in,
                              void* d_out, int out_size, void* d_ws, size_t ws_size,
                              hipStream_t stream) {
    const float* x    = (const float*)d_in[0];
    const int*   ei   = (const int*)d_in[1];
    const float* W1   = (const float*)d_in[2];
    const float* as1w = (const float*)d_in[3];
    const float* ad1w = (const float*)d_in[4];
    const float* b1   = (const float*)d_in[5];
    const float* W2   = (const float*)d_in[6];
    const float* as2w = (const float*)d_in[7];
    const float* ad2w = (const float*)d_in[8];
    const float* b2   = (const float*)d_in[9];
    float* out = (float*)d_out;

    const int n = in_sizes[0] / 256;      // 50000
    const int E = in_sizes[1] / 2;        // 1600000
    const int tot = E + n;
    const int nbk = (n + BWIDTH - 1) / BWIDTH;   // 391

    char* p = (char*)d_ws;
    auto alloc = [&](size_t bytes) {
        void* r = (void*)p;
        p += (bytes + 255) & ~(size_t)255;
        return r;
    };
    int*   offs  = (int*)alloc((size_t)(n + 1) * 4);
    int*   srcs  = (int*)alloc((size_t)tot * 4);
    int2*  tmp   = (int2*)alloc((size_t)E * 8);
    int*   bcnt  = (int*)alloc(512 * 4);
    int*   bbase = (int*)alloc(512 * 4);
    int*   bcur  = (int*)alloc(512 * 4);
    __hip_bfloat16* W1t = (__hip_bfloat16*)alloc((size_t)128 * 256 * 2);
    __hip_bfloat16* W2t = (__hip_bfloat16*)alloc((size_t)64 * 128 * 2);
    __hip_bfloat16* h1  = (__hip_bfloat16*)alloc((size_t)n * 128 * 2);
    __hip_bfloat16* out1= (__hip_bfloat16*)alloc((size_t)n * 128 * 2);
    __hip_bfloat16* h2  = (__hip_bfloat16*)alloc((size_t)n * 64 * 2);
    float* a_s1 = (float*)alloc((size_t)n * 2 * 4);
    float* a_d1 = (float*)alloc((size_t)n * 2 * 4);
    float* a_s2 = (float*)alloc((size_t)n * 4);
    float* a_d2 = (float*)alloc((size_t)n * 4);

    int pblocks = (E + PCHUNK - 1) / PCHUNK;    // 391

    // --- bucketed CSR build ---
    zero_buf<<<2, 256, 0, stream>>>(bcnt, 512);
    bucket_hist<<<pblocks, 256, 0, stream>>>(ei, E, bcnt);
    bucket_scan<<<1, 512, 0, stream>>>(bcnt, bbase, bcur, nbk, n);
    partition_edges<<<pblocks, 256, 0, stream>>>(ei, E, bcur, tmp);
    bucket_csr<<<nbk, 256, 0, stream>>>(bbase, tmp, offs, srcs, n, nbk);

    // --- weight prep ---
    transpose_w<<<(128 * 256 + 255) / 256, 256, 0, stream>>>(W1, W1t, 256, 128);
    transpose_w<<<(64 * 128 + 255) / 256, 256, 0, stream>>>(W2, W2t, 128, 64);

    // --- Layer 1 ---
    gemm_mfma<false, 8><<<(n + 63) / 64, 256, 0, stream>>>(x, W1t, h1, n, 256);
    att_dots<2><<<(n * 64 + 255) / 256, 256, 0, stream>>>(h1, as1w, ad1w, a_s1, a_d1, n);
    edge_agg_l1<<<(n * 64 + 255) / 256, 256, 0, stream>>>(offs, srcs, h1, a_s1, a_d1, b1, out1, n);

    // --- Layer 2 ---
    gemm_mfma<true, 4><<<(n + 63) / 64, 256, 0, stream>>>(out1, W2t, h2, n, 128);
    att_dots<1><<<(n * 64 + 255) / 256, 256, 0, stream>>>(h2, as2w, ad2w, a_s2, a_d2, n);
    edge_agg_l2<<<(n * 64 + 255) / 256, 256, 0, stream>>>(offs, srcs, h2, a_s2, a_d2, b2, out, n);
}

// Round 4
// 351.100 us; speedup vs baseline: 2.0932x; 1.0551x over previous
//
#include <hip/hip_runtime.h>
#include <hip/hip_bf16.h>
#include <math.h>

typedef short bf16x8 __attribute__((ext_vector_type(8)));
typedef float f32x4 __attribute__((ext_vector_type(4)));

#define BSHIFT 7
#define BWIDTH 128      // nodes per bucket
#define PCHUNK 4096     // edges per partition block

// ---------------------------------------------------------------------------
// Bucketed CSR build (group edges by dst, self-loops appended analytically)
// ---------------------------------------------------------------------------

__global__ void zero_buf(int* __restrict__ p, int n) {
    int i = blockIdx.x * blockDim.x + threadIdx.x;
    if (i < n) p[i] = 0;
}

__global__ __launch_bounds__(256) void bucket_hist(const int* __restrict__ ei, int E,
                                                   int* __restrict__ bcnt) {
    __shared__ int h[512];
    int tid = threadIdx.x;
    for (int i = tid; i < 512; i += 256) h[i] = 0;
    __syncthreads();
    int start = blockIdx.x * PCHUNK;
    int cnt = min(PCHUNK, E - start);
    for (int i = tid; i < cnt; i += 256)
        atomicAdd(&h[ei[E + start + i] >> BSHIFT], 1);
    __syncthreads();
    for (int i = tid; i < 512; i += 256)
        if (h[i]) atomicAdd(&bcnt[i], h[i]);
}

__global__ __launch_bounds__(512) void bucket_scan(const int* __restrict__ bcnt,
                                                   int* __restrict__ bbase,
                                                   int* __restrict__ bcur,
                                                   int nbk, int n) {
    __shared__ int s[512];
    int tid = threadIdx.x;
    int nodes = 0;
    if (tid < nbk) nodes = min(BWIDTH, n - (tid << BSHIFT));
    int v = (tid < nbk) ? bcnt[tid] + nodes : 0;
    s[tid] = v;
    __syncthreads();
    #pragma unroll
    for (int o = 1; o < 512; o <<= 1) {
        int t = (tid >= o) ? s[tid - o] : 0;
        __syncthreads();
        s[tid] += t;
        __syncthreads();
    }
    if (tid < nbk) {
        int ex = s[tid] - v;
        bbase[tid] = ex;
        bcur[tid] = ex - (tid << BSHIFT);
    }
    if (tid == nbk) bbase[nbk] = s[tid];
}

__global__ __launch_bounds__(256) void partition_edges(const int* __restrict__ ei, int E,
                                                       int* __restrict__ bcur,
                                                       int2* __restrict__ tmp) {
    __shared__ int2 stage[PCHUNK];
    __shared__ int h[512];
    __shared__ int lbase[512];
    int tid = threadIdx.x;
    int start = blockIdx.x * PCHUNK;
    int cnt = min(PCHUNK, E - start);
    for (int i = tid; i < 512; i += 256) h[i] = 0;
    __syncthreads();
    for (int i = tid; i < cnt; i += 256) {
        int s = ei[start + i];
        int d = ei[E + start + i];
        stage[i] = make_int2(s, d);
        atomicAdd(&h[d >> BSHIFT], 1);
    }
    __syncthreads();
    for (int i = tid; i < 512; i += 256) {
        if (h[i] > 0) lbase[i] = atomicAdd(&bcur[i], h[i]);
        h[i] = 0;
    }
    __syncthreads();
    for (int i = tid; i < cnt; i += 256) {
        int2 e = stage[i];
        int b = e.y >> BSHIFT;
        int r = atomicAdd(&h[b], 1);
        tmp[lbase[b] + r] = e;
    }
}

__global__ __launch_bounds__(256) void bucket_csr(const int* __restrict__ bbase,
                                                  const int2* __restrict__ tmp,
                                                  int* __restrict__ offs,
                                                  int* __restrict__ srcs,
                                                  int n, int nbk) {
    __shared__ int cnt[BWIDTH];
    __shared__ int sa[BWIDTH];
    __shared__ int cur[BWIDTH];
    int b = blockIdx.x;
    int tid = threadIdx.x;
    int node0 = b << BSHIFT;
    int nnodes = min(BWIDTH, n - node0);
    int cb = bbase[b];
    int ce = bbase[b + 1];
    int tb = cb - node0;
    int ecnt = (ce - cb) - nnodes;

    if (tid < BWIDTH) cnt[tid] = (tid < nnodes) ? 1 : 0;
    __syncthreads();
    for (int i = tid; i < ecnt; i += 256)
        atomicAdd(&cnt[tmp[tb + i].y & (BWIDTH - 1)], 1);
    __syncthreads();
    if (tid < BWIDTH) sa[tid] = cnt[tid];
    __syncthreads();
    #pragma unroll
    for (int o = 1; o < BWIDTH; o <<= 1) {
        int v = 0;
        if (tid < BWIDTH) { v = sa[tid]; if (tid >= o) v += sa[tid - o]; }
        __syncthreads();
        if (tid < BWIDTH) sa[tid] = v;
        __syncthreads();
    }
    if (tid < BWIDTH) {
        int ex = sa[tid] - cnt[tid];
        if (tid < nnodes) {
            offs[node0 + tid] = cb + ex;
            srcs[cb + ex] = node0 + tid;
        }
        cur[tid] = ex + (tid < nnodes ? 1 : 0);
    }
    if (b == nbk - 1 && tid == 0) offs[n] = ce;
    __syncthreads();
    for (int i = tid; i < ecnt; i += 256) {
        int2 e = tmp[tb + i];
        int li = e.y & (BWIDTH - 1);
        int r = atomicAdd(&cur[li], 1);
        srcs[cb + r] = e.x;
    }
}

// ---------------------------------------------------------------------------
// Weight prep: Wt[n][k] = (bf16) W[k][n]
// ---------------------------------------------------------------------------
__global__ void transpose_w(const float* __restrict__ W, __hip_bfloat16* __restrict__ Wt,
                            int K, int N) {
    int idx = blockIdx.x * blockDim.x + threadIdx.x;
    if (idx >= K * N) return;
    int nn = idx / K, kk = idx % K;
    Wt[idx] = __float2bfloat16(W[(size_t)kk * N + nn]);
}

// ---------------------------------------------------------------------------
// MFMA bf16 GEMM + fused attention dots.
// C[M,N](bf16) = A[M,K] @ Bt[N,K]^T ;  a_s/a_d[row(,h)] = <C_row, att(head)>
// ---------------------------------------------------------------------------
template <bool A_BF16, int NT, int HEADS>
__global__ __launch_bounds__(256) void gemm_att(
    const void* __restrict__ Av, const __hip_bfloat16* __restrict__ Bt,
    __hip_bfloat16* __restrict__ C,
    const float* __restrict__ atts, const float* __restrict__ attd,
    float* __restrict__ a_s, float* __restrict__ a_d, int M, int K) {
    constexpr int N = NT * 16;
    __shared__ __hip_bfloat16 As[64][40];
    int tid = threadIdx.x;
    int w = tid >> 6, l = tid & 63;
    int q = l >> 4, m16 = l & 15;
    int bm = blockIdx.x * 64;

    int lr = tid >> 2, lseg = tid & 3;
    int arow = bm + lr; if (arow >= M) arow = M - 1;

    f32x4 acc[NT];
    #pragma unroll
    for (int t = 0; t < NT; t++) acc[t] = (f32x4){0.f, 0.f, 0.f, 0.f};

    for (int kc = 0; kc < K; kc += 32) {
        if (A_BF16) {
            const __hip_bfloat16* A = (const __hip_bfloat16*)Av;
            uint4 v = *(const uint4*)(A + (size_t)arow * K + kc + lseg * 8);
            *(uint4*)&As[lr][lseg * 8] = v;
        } else {
            const float* A = (const float*)Av;
            float4 v0 = *(const float4*)(A + (size_t)arow * K + kc + lseg * 8);
            float4 v1 = *(const float4*)(A + (size_t)arow * K + kc + lseg * 8 + 4);
            union { __hip_bfloat16 h[8]; uint4 u; } tmp;
            tmp.h[0] = __float2bfloat16(v0.x); tmp.h[1] = __float2bfloat16(v0.y);
            tmp.h[2] = __float2bfloat16(v0.z); tmp.h[3] = __float2bfloat16(v0.w);
            tmp.h[4] = __float2bfloat16(v1.x); tmp.h[5] = __float2bfloat16(v1.y);
            tmp.h[6] = __float2bfloat16(v1.z); tmp.h[7] = __float2bfloat16(v1.w);
            *(uint4*)&As[lr][lseg * 8] = tmp.u;
        }
        __syncthreads();
        bf16x8 a = *(const bf16x8*)&As[w * 16 + m16][q * 8];
        #pragma unroll
        for (int t = 0; t < NT; t++) {
            bf16x8 b = *(const bf16x8*)(Bt + (size_t)(t * 16 + m16) * K + kc + q * 8);
            acc[t] = __builtin_amdgcn_mfma_f32_16x16x32_bf16(a, b, acc[t], 0, 0, 0);
        }
        __syncthreads();
    }

    // store C
    #pragma unroll
    for (int t = 0; t < NT; t++) {
        #pragma unroll
        for (int r = 0; r < 4; r++) {
            int row = bm + w * 16 + q * 4 + r;
            if (row < M) C[(size_t)row * N + t * 16 + m16] = __float2bfloat16(acc[t][r]);
        }
    }

    // fused attention dots: per row, per head: sum over channels
    float ps[HEADS][4], pd[HEADS][4];
    #pragma unroll
    for (int hh = 0; hh < HEADS; hh++)
        #pragma unroll
        for (int r = 0; r < 4; r++) { ps[hh][r] = 0.f; pd[hh][r] = 0.f; }
    #pragma unroll
    for (int t = 0; t < NT; t++) {
        int ch = t * 16 + m16;
        float asw = atts[ch], adw = attd[ch];
        int hh = (HEADS == 2) ? (t >> 2) : 0;
        #pragma unroll
        for (int r = 0; r < 4; r++) {
            ps[hh][r] = fmaf(acc[t][r], asw, ps[hh][r]);
            pd[hh][r] = fmaf(acc[t][r], adw, pd[hh][r]);
        }
    }
    #pragma unroll
    for (int o = 1; o < 16; o <<= 1) {
        #pragma unroll
        for (int hh = 0; hh < HEADS; hh++)
            #pragma unroll
            for (int r = 0; r < 4; r++) {
                ps[hh][r] += __shfl_xor(ps[hh][r], o);
                pd[hh][r] += __shfl_xor(pd[hh][r], o);
            }
    }
    if (m16 == 0) {
        #pragma unroll
        for (int r = 0; r < 4; r++) {
            int row = bm + w * 16 + q * 4 + r;
            if (row < M) {
                if (HEADS == 2) {
                    a_s[row * 2]     = ps[0][r];
                    a_s[row * 2 + 1] = ps[1][r];
                    a_d[row * 2]     = pd[0][r];
                    a_d[row * 2 + 1] = pd[1][r];
                } else {
                    a_s[row] = ps[0][r];
                    a_d[row] = pd[0][r];
                }
            }
        }
    }
}

__device__ __forceinline__ float leaky(float r) {
    return r < 0.f ? 0.2f * r : r;
}

// ---------------------------------------------------------------------------
// Edge softmax + aggregation, layer 1 (heads=2). Wave per dst node.
// Batched weights: lanes 0-31 compute head-0 weights for a 32-edge batch,
// lanes 32-63 head-1; gather loop pulls w/src via shuffle (no exp per edge).
// ---------------------------------------------------------------------------
__global__ __launch_bounds__(256) void edge_agg_l1(
    const int* __restrict__ offs, const int* __restrict__ srcs,
    const __hip_bfloat16* __restrict__ h1, const float* __restrict__ asv,
    const float* __restrict__ adv, const float* __restrict__ bias,
    __hip_bfloat16* __restrict__ out, int n) {
    int d = (blockIdx.x * blockDim.x + threadIdx.x) >> 6;
    int lane = threadIdx.x & 63;
    if (d >= n) return;
    int start = offs[d], end = offs[d + 1];
    float ad0 = adv[2 * d], ad1 = adv[2 * d + 1];

    // pass 1: online softmax stats (per-lane strided, then wave merge)
    float m0 = -3.4e38f, m1 = -3.4e38f, s0 = 0.f, s1 = 0.f;
    for (int e = start + lane; e < end; e += 64) {
        int s = srcs[e];
        float2 a = *(const float2*)(asv + 2 * s);
        float r0 = leaky(a.x + ad0);
        float r1 = leaky(a.y + ad1);
        if (r0 > m0) { s0 *= __expf(m0 - r0); m0 = r0; }
        s0 += __expf(r0 - m0);
        if (r1 > m1) { s1 *= __expf(m1 - r1); m1 = r1; }
        s1 += __expf(r1 - m1);
    }
    #pragma unroll
    for (int o = 1; o < 64; o <<= 1) {
        float om0 = __shfl_xor(m0, o), os0 = __shfl_xor(s0, o);
        float nm0 = fmaxf(m0, om0);
        s0 = s0 * __expf(m0 - nm0) + os0 * __expf(om0 - nm0);
        m0 = nm0;
        float om1 = __shfl_xor(m1, o), os1 = __shfl_xor(s1, o);
        float nm1 = fmaxf(m1, om1);
        s1 = s1 * __expf(m1 - nm1) + os1 * __expf(om1 - nm1);
        m1 = nm1;
    }
    float inv0 = 1.f / (s0 + 1e-16f), inv1 = 1.f / (s1 + 1e-16f);

    int hsel = lane >> 5;            // head this lane's weight/channels belong to
    int hoff = hsel << 5;
    float mh = hsel ? m1 : m0;
    float invh = hsel ? inv1 : inv0;
    float adh = hsel ? ad1 : ad0;
    int c = lane * 2;                // channels c, c+1
    float ax0 = 0.f, ay0 = 0.f, ax1 = 0.f, ay1 = 0.f;

    for (int base = start; base < end; base += 32) {
        int cnt = min(32, end - base);
        float wv = 0.f;
        int sv = 0;
        if ((lane & 31) < cnt) {
            sv = srcs[base + (lane & 31)];
            wv = __expf(leaky(asv[2 * sv + hsel] + adh) - mh) * invh;
        }
        int j = 0;
        for (; j + 2 <= cnt; j += 2) {
            float w0 = __shfl(wv, j + hoff);
            float w1 = __shfl(wv, j + 1 + hoff);
            int sj0 = __shfl(sv, j);
            int sj1 = __shfl(sv, j + 1);
            __hip_bfloat162 v0 = *(const __hip_bfloat162*)(h1 + (size_t)sj0 * 128 + c);
            __hip_bfloat162 v1 = *(const __hip_bfloat162*)(h1 + (size_t)sj1 * 128 + c);
            ax0 = fmaf(w0, __bfloat162float(v0.x), ax0);
            ay0 = fmaf(w0, __bfloat162float(v0.y), ay0);
            ax1 = fmaf(w1, __bfloat162float(v1.x), ax1);
            ay1 = fmaf(w1, __bfloat162float(v1.y), ay1);
        }
        if (j < cnt) {
            float w0 = __shfl(wv, j + hoff);
            int sj0 = __shfl(sv, j);
            __hip_bfloat162 v0 = *(const __hip_bfloat162*)(h1 + (size_t)sj0 * 128 + c);
            ax0 = fmaf(w0, __bfloat162float(v0.x), ax0);
            ay0 = fmaf(w0, __bfloat162float(v0.y), ay0);
        }
    }
    float ox = fmaxf(ax0 + ax1 + bias[c], 0.f);
    float oy = fmaxf(ay0 + ay1 + bias[c + 1], 0.f);
    __hip_bfloat162 o2;
    o2.x = __float2bfloat16(ox);
    o2.y = __float2bfloat16(oy);
    *(__hip_bfloat162*)(out + (size_t)d * 128 + c) = o2;
}

// ---------------------------------------------------------------------------
// Edge softmax + aggregation, layer 2 (heads=1) + bias + log_softmax.
// Batched weights over 64-edge batches.
// ---------------------------------------------------------------------------
__global__ __launch_bounds__(256) void edge_agg_l2(
    const int* __restrict__ offs, const int* __restrict__ srcs,
    const __hip_bfloat16* __restrict__ h2, const float* __restrict__ asv,
    const float* __restrict__ adv, const float* __restrict__ bias,
    float* __restrict__ out, int n) {
    int d = (blockIdx.x * blockDim.x + threadIdx.x) >> 6;
    int lane = threadIdx.x & 63;
    if (d >= n) return;
    int start = offs[d], end = offs[d + 1];
    float ad = adv[d];

    float m = -3.4e38f, ssum = 0.f;
    for (int e = start + lane; e < end; e += 64) {
        int s = srcs[e];
        float r = leaky(asv[s] + ad);
        if (r > m) { ssum *= __expf(m - r); m = r; }
        ssum += __expf(r - m);
    }
    #pragma unroll
    for (int o = 1; o < 64; o <<= 1) {
        float om = __shfl_xor(m, o), os = __shfl_xor(ssum, o);
        float nm = fmaxf(m, om);
        ssum = ssum * __expf(m - nm) + os * __expf(om - nm);
        m = nm;
    }
    float inv = 1.f / (ssum + 1e-16f);

    float a0 = 0.f, a1 = 0.f;
    for (int base = start; base < end; base += 64) {
        int cnt = min(64, end - base);
        float wv = 0.f;
        int sv = 0;
        if (lane < cnt) {
            sv = srcs[base + lane];
            wv = __expf(leaky(asv[sv] + ad) - m) * inv;
        }
        int j = 0;
        for (; j + 2 <= cnt; j += 2) {
            float w0 = __shfl(wv, j);
            float w1 = __shfl(wv, j + 1);
            int sj0 = __shfl(sv, j);
            int sj1 = __shfl(sv, j + 1);
            float v0 = __bfloat162float(h2[(size_t)sj0 * 64 + lane]);
            float v1 = __bfloat162float(h2[(size_t)sj1 * 64 + lane]);
            a0 = fmaf(w0, v0, a0);
            a1 = fmaf(w1, v1, a1);
        }
        if (j < cnt) {
            float w0 = __shfl(wv, j);
            int sj0 = __shfl(sv, j);
            a0 = fmaf(w0, __bfloat162float(h2[(size_t)sj0 * 64 + lane]), a0);
        }
    }
    float v = a0 + a1 + bias[lane];

    float vm = v;
    #pragma unroll
    for (int o = 1; o < 64; o <<= 1) vm = fmaxf(vm, __shfl_xor(vm, o));
    float ex = __expf(v - vm);
    float se = ex;
    #pragma unroll
    for (int o = 1; o < 64; o <<= 1) se += __shfl_xor(se, o);
    out[(size_t)d * 64 + lane] = v - vm - logf(se);
}

// ---------------------------------------------------------------------------
// Launch
// ---------------------------------------------------------------------------
extern "C" void kernel_launch(void* const* d_in, const int* in_sizes, int n_in,
                              void* d_out, int out_size, void* d_ws, size_t ws_size,
                              hipStream_t stream) {
    const float* x    = (const float*)d_in[0];
    const int*   ei   = (const int*)d_in[1];
    const float* W1   = (const float*)d_in[2];
    const float* as1w = (const float*)d_in[3];
    const float* ad1w = (const float*)d_in[4];
    const float* b1   = (const float*)d_in[5];
    const float* W2   = (const float*)d_in[6];
    const float* as2w = (const float*)d_in[7];
    const float* ad2w = (const float*)d_in[8];
    const float* b2   = (const float*)d_in[9];
    float* out = (float*)d_out;

    const int n = in_sizes[0] / 256;      // 50000
    const int E = in_sizes[1] / 2;        // 1600000
    const int tot = E + n;
    const int nbk = (n + BWIDTH - 1) / BWIDTH;

    char* p = (char*)d_ws;
    auto alloc = [&](size_t bytes) {
        void* r = (void*)p;
        p += (bytes + 255) & ~(size_t)255;
        return r;
    };
    int*   offs  = (int*)alloc((size_t)(n + 1) * 4);
    int*   srcs  = (int*)alloc((size_t)tot * 4);
    int2*  tmp   = (int2*)alloc((size_t)E * 8);
    int*   bcnt  = (int*)alloc(512 * 4);
    int*   bbase = (int*)alloc(512 * 4);
    int*   bcur  = (int*)alloc(512 * 4);
    __hip_bfloat16* W1t = (__hip_bfloat16*)alloc((size_t)128 * 256 * 2);
    __hip_bfloat16* W2t = (__hip_bfloat16*)alloc((size_t)64 * 128 * 2);
    __hip_bfloat16* h1  = (__hip_bfloat16*)alloc((size_t)n * 128 * 2);
    __hip_bfloat16* out1= (__hip_bfloat16*)alloc((size_t)n * 128 * 2);
    __hip_bfloat16* h2  = (__hip_bfloat16*)alloc((size_t)n * 64 * 2);
    float* a_s1 = (float*)alloc((size_t)n * 2 * 4);
    float* a_d1 = (float*)alloc((size_t)n * 2 * 4);
    float* a_s2 = (float*)alloc((size_t)n * 4);
    float* a_d2 = (float*)alloc((size_t)n * 4);

    int pblocks = (E + PCHUNK - 1) / PCHUNK;

    // --- bucketed CSR build ---
    zero_buf<<<2, 256, 0, stream>>>(bcnt, 512);
    bucket_hist<<<pblocks, 256, 0, stream>>>(ei, E, bcnt);
    bucket_scan<<<1, 512, 0, stream>>>(bcnt, bbase, bcur, nbk, n);
    partition_edges<<<pblocks, 256, 0, stream>>>(ei, E, bcur, tmp);
    bucket_csr<<<nbk, 256, 0, stream>>>(bbase, tmp, offs, srcs, n, nbk);

    // --- weight prep ---
    transpose_w<<<(128 * 256 + 255) / 256, 256, 0, stream>>>(W1, W1t, 256, 128);
    transpose_w<<<(64 * 128 + 255) / 256, 256, 0, stream>>>(W2, W2t, 128, 64);

    // --- Layer 1 ---
    gemm_att<false, 8, 2><<<(n + 63) / 64, 256, 0, stream>>>(
        x, W1t, h1, as1w, ad1w, a_s1, a_d1, n, 256);
    edge_agg_l1<<<(n * 64 + 255) / 256, 256, 0, stream>>>(offs, srcs, h1, a_s1, a_d1, b1, out1, n);

    // --- Layer 2 ---
    gemm_att<true, 4, 1><<<(n + 63) / 64, 256, 0, stream>>>(
        out1, W2t, h2, as2w, ad2w, a_s2, a_d2, n, 128);
    edge_agg_l2<<<(n * 64 + 255) / 256, 256, 0, stream>>>(offs, srcs, h2, a_s2, a_d2, b2, out, n);
}

// Round 5
// 306.149 us; speedup vs baseline: 2.4005x; 1.1468x over previous
//
#include <hip/hip_runtime.h>
#include <hip/hip_bf16.h>
#include <math.h>

typedef short bf16x8 __attribute__((ext_vector_type(8)));
typedef float f32x4 __attribute__((ext_vector_type(4)));

#define BSHIFT 7
#define BWIDTH 128      // nodes per bucket
#define PCHUNK 4096     // edges per partition block

// ---------------------------------------------------------------------------
// Bucketed CSR build (group edges by dst, self-loops appended analytically)
// ---------------------------------------------------------------------------

__global__ void zero_buf(int* __restrict__ p, int n) {
    int i = blockIdx.x * blockDim.x + threadIdx.x;
    if (i < n) p[i] = 0;
}

__global__ __launch_bounds__(256) void bucket_hist(const int* __restrict__ ei, int E,
                                                   int* __restrict__ bcnt) {
    __shared__ int h[512];
    int tid = threadIdx.x;
    for (int i = tid; i < 512; i += 256) h[i] = 0;
    __syncthreads();
    int start = blockIdx.x * PCHUNK;
    int cnt = min(PCHUNK, E - start);
    for (int i = tid; i < cnt; i += 256)
        atomicAdd(&h[ei[E + start + i] >> BSHIFT], 1);
    __syncthreads();
    for (int i = tid; i < 512; i += 256)
        if (h[i]) atomicAdd(&bcnt[i], h[i]);
}

__global__ __launch_bounds__(512) void bucket_scan(const int* __restrict__ bcnt,
                                                   int* __restrict__ bbase,
                                                   int* __restrict__ bcur,
                                                   int nbk, int n) {
    __shared__ int s[512];
    int tid = threadIdx.x;
    int nodes = 0;
    if (tid < nbk) nodes = min(BWIDTH, n - (tid << BSHIFT));
    int v = (tid < nbk) ? bcnt[tid] + nodes : 0;
    s[tid] = v;
    __syncthreads();
    #pragma unroll
    for (int o = 1; o < 512; o <<= 1) {
        int t = (tid >= o) ? s[tid - o] : 0;
        __syncthreads();
        s[tid] += t;
        __syncthreads();
    }
    if (tid < nbk) {
        int ex = s[tid] - v;
        bbase[tid] = ex;
        bcur[tid] = ex - (tid << BSHIFT);
    }
    if (tid == nbk) bbase[nbk] = s[tid];
}

__global__ __launch_bounds__(256) void partition_edges(const int* __restrict__ ei, int E,
                                                       int* __restrict__ bcur,
                                                       int2* __restrict__ tmp) {
    __shared__ int2 stage[PCHUNK];
    __shared__ int h[512];
    __shared__ int lbase[512];
    int tid = threadIdx.x;
    int start = blockIdx.x * PCHUNK;
    int cnt = min(PCHUNK, E - start);
    for (int i = tid; i < 512; i += 256) h[i] = 0;
    __syncthreads();
    for (int i = tid; i < cnt; i += 256) {
        int s = ei[start + i];
        int d = ei[E + start + i];
        stage[i] = make_int2(s, d);
        atomicAdd(&h[d >> BSHIFT], 1);
    }
    __syncthreads();
    for (int i = tid; i < 512; i += 256) {
        if (h[i] > 0) lbase[i] = atomicAdd(&bcur[i], h[i]);
        h[i] = 0;
    }
    __syncthreads();
    for (int i = tid; i < cnt; i += 256) {
        int2 e = stage[i];
        int b = e.y >> BSHIFT;
        int r = atomicAdd(&h[b], 1);
        tmp[lbase[b] + r] = e;
    }
}

__global__ __launch_bounds__(256) void bucket_csr(const int* __restrict__ bbase,
                                                  const int2* __restrict__ tmp,
                                                  int* __restrict__ offs,
                                                  int* __restrict__ srcs,
                                                  int n, int nbk) {
    __shared__ int cnt[BWIDTH];
    __shared__ int sa[BWIDTH];
    __shared__ int cur[BWIDTH];
    int b = blockIdx.x;
    int tid = threadIdx.x;
    int node0 = b << BSHIFT;
    int nnodes = min(BWIDTH, n - node0);
    int cb = bbase[b];
    int ce = bbase[b + 1];
    int tb = cb - node0;
    int ecnt = (ce - cb) - nnodes;

    if (tid < BWIDTH) cnt[tid] = (tid < nnodes) ? 1 : 0;
    __syncthreads();
    for (int i = tid; i < ecnt; i += 256)
        atomicAdd(&cnt[tmp[tb + i].y & (BWIDTH - 1)], 1);
    __syncthreads();
    if (tid < BWIDTH) sa[tid] = cnt[tid];
    __syncthreads();
    #pragma unroll
    for (int o = 1; o < BWIDTH; o <<= 1) {
        int v = 0;
        if (tid < BWIDTH) { v = sa[tid]; if (tid >= o) v += sa[tid - o]; }
        __syncthreads();
        if (tid < BWIDTH) sa[tid] = v;
        __syncthreads();
    }
    if (tid < BWIDTH) {
        int ex = sa[tid] - cnt[tid];
        if (tid < nnodes) {
            offs[node0 + tid] = cb + ex;
            srcs[cb + ex] = node0 + tid;
        }
        cur[tid] = ex + (tid < nnodes ? 1 : 0);
    }
    if (b == nbk - 1 && tid == 0) offs[n] = ce;
    __syncthreads();
    for (int i = tid; i < ecnt; i += 256) {
        int2 e = tmp[tb + i];
        int li = e.y & (BWIDTH - 1);
        int r = atomicAdd(&cur[li], 1);
        srcs[cb + r] = e.x;
    }
}

// ---------------------------------------------------------------------------
// Weight prep (both layers in one launch): Wt[n][k] = (bf16) W[k][n]
// ---------------------------------------------------------------------------
__global__ void transpose_both(const float* __restrict__ W1, const float* __restrict__ W2,
                               __hip_bfloat16* __restrict__ W1t,
                               __hip_bfloat16* __restrict__ W2t) {
    int idx = blockIdx.x * blockDim.x + threadIdx.x;
    const int n1 = 128 * 256;
    if (idx < n1) {
        int nn = idx >> 8, kk = idx & 255;
        W1t[idx] = __float2bfloat16(W1[kk * 128 + nn]);
    } else {
        int j = idx - n1;
        if (j < 64 * 128) {
            int nn = j >> 7, kk = j & 127;
            W2t[j] = __float2bfloat16(W2[kk * 64 + nn]);
        }
    }
}

// ---------------------------------------------------------------------------
// MFMA bf16 GEMM + fused attention dots.
// ---------------------------------------------------------------------------
template <bool A_BF16, int NT, int HEADS>
__global__ __launch_bounds__(256) void gemm_att(
    const void* __restrict__ Av, const __hip_bfloat16* __restrict__ Bt,
    __hip_bfloat16* __restrict__ C,
    const float* __restrict__ atts, const float* __restrict__ attd,
    float* __restrict__ a_s, float* __restrict__ a_d, int M, int K) {
    constexpr int N = NT * 16;
    __shared__ __hip_bfloat16 As[64][40];
    int tid = threadIdx.x;
    int w = tid >> 6, l = tid & 63;
    int q = l >> 4, m16 = l & 15;
    int bm = blockIdx.x * 64;

    int lr = tid >> 2, lseg = tid & 3;
    int arow = bm + lr; if (arow >= M) arow = M - 1;

    f32x4 acc[NT];
    #pragma unroll
    for (int t = 0; t < NT; t++) acc[t] = (f32x4){0.f, 0.f, 0.f, 0.f};

    for (int kc = 0; kc < K; kc += 32) {
        if (A_BF16) {
            const __hip_bfloat16* A = (const __hip_bfloat16*)Av;
            uint4 v = *(const uint4*)(A + (size_t)arow * K + kc + lseg * 8);
            *(uint4*)&As[lr][lseg * 8] = v;
        } else {
            const float* A = (const float*)Av;
            float4 v0 = *(const float4*)(A + (size_t)arow * K + kc + lseg * 8);
            float4 v1 = *(const float4*)(A + (size_t)arow * K + kc + lseg * 8 + 4);
            union { __hip_bfloat16 h[8]; uint4 u; } tmp;
            tmp.h[0] = __float2bfloat16(v0.x); tmp.h[1] = __float2bfloat16(v0.y);
            tmp.h[2] = __float2bfloat16(v0.z); tmp.h[3] = __float2bfloat16(v0.w);
            tmp.h[4] = __float2bfloat16(v1.x); tmp.h[5] = __float2bfloat16(v1.y);
            tmp.h[6] = __float2bfloat16(v1.z); tmp.h[7] = __float2bfloat16(v1.w);
            *(uint4*)&As[lr][lseg * 8] = tmp.u;
        }
        __syncthreads();
        bf16x8 a = *(const bf16x8*)&As[w * 16 + m16][q * 8];
        #pragma unroll
        for (int t = 0; t < NT; t++) {
            bf16x8 b = *(const bf16x8*)(Bt + (size_t)(t * 16 + m16) * K + kc + q * 8);
            acc[t] = __builtin_amdgcn_mfma_f32_16x16x32_bf16(a, b, acc[t], 0, 0, 0);
        }
        __syncthreads();
    }

    #pragma unroll
    for (int t = 0; t < NT; t++) {
        #pragma unroll
        for (int r = 0; r < 4; r++) {
            int row = bm + w * 16 + q * 4 + r;
            if (row < M) C[(size_t)row * N + t * 16 + m16] = __float2bfloat16(acc[t][r]);
        }
    }

    float ps[HEADS][4], pd[HEADS][4];
    #pragma unroll
    for (int hh = 0; hh < HEADS; hh++)
        #pragma unroll
        for (int r = 0; r < 4; r++) { ps[hh][r] = 0.f; pd[hh][r] = 0.f; }
    #pragma unroll
    for (int t = 0; t < NT; t++) {
        int ch = t * 16 + m16;
        float asw = atts[ch], adw = attd[ch];
        int hh = (HEADS == 2) ? (t >> 2) : 0;
        #pragma unroll
        for (int r = 0; r < 4; r++) {
            ps[hh][r] = fmaf(acc[t][r], asw, ps[hh][r]);
            pd[hh][r] = fmaf(acc[t][r], adw, pd[hh][r]);
        }
    }
    #pragma unroll
    for (int o = 1; o < 16; o <<= 1) {
        #pragma unroll
        for (int hh = 0; hh < HEADS; hh++)
            #pragma unroll
            for (int r = 0; r < 4; r++) {
                ps[hh][r] += __shfl_xor(ps[hh][r], o);
                pd[hh][r] += __shfl_xor(pd[hh][r], o);
            }
    }
    if (m16 == 0) {
        #pragma unroll
        for (int r = 0; r < 4; r++) {
            int row = bm + w * 16 + q * 4 + r;
            if (row < M) {
                if (HEADS == 2) {
                    a_s[row * 2]     = ps[0][r];
                    a_s[row * 2 + 1] = ps[1][r];
                    a_d[row * 2]     = pd[0][r];
                    a_d[row * 2 + 1] = pd[1][r];
                } else {
                    a_s[row] = ps[0][r];
                    a_d[row] = pd[0][r];
                }
            }
        }
    }
}

__device__ __forceinline__ float leaky(float r) {
    return r < 0.f ? 0.2f * r : r;
}

__device__ __forceinline__ void unpack2(unsigned u, float& lo, float& hi) {
    lo = __uint_as_float(u << 16);
    hi = __uint_as_float(u & 0xffff0000u);
}

// ---------------------------------------------------------------------------
// Edge softmax + aggregation, layer 1 (heads=2). Wave per dst node.
// Wide gather: 16 lanes x dwordx4 cover one 256-B row -> 4 edges per load.
//   lane = g*16 + sub ; g = edge subgroup (0..3), sub = channel segment,
//   channels [sub*8, sub*8+8), head = sub>>3.
// ---------------------------------------------------------------------------
__global__ __launch_bounds__(256) void edge_agg_l1(
    const int* __restrict__ offs, const int* __restrict__ srcs,
    const __hip_bfloat16* __restrict__ h1, const float* __restrict__ asv,
    const float* __restrict__ adv, const float* __restrict__ bias,
    __hip_bfloat16* __restrict__ out, int n) {
    int d = (blockIdx.x * blockDim.x + threadIdx.x) >> 6;
    int lane = threadIdx.x & 63;
    if (d >= n) return;
    int start = offs[d], end = offs[d + 1];
    float ad0 = adv[2 * d], ad1 = adv[2 * d + 1];

    // pass 1: online softmax stats
    float m0 = -3.4e38f, m1 = -3.4e38f, s0 = 0.f, s1 = 0.f;
    for (int e = start + lane; e < end; e += 64) {
        int s = srcs[e];
        float2 a = *(const float2*)(asv + 2 * s);
        float r0 = leaky(a.x + ad0);
        float r1 = leaky(a.y + ad1);
        if (r0 > m0) { s0 *= __expf(m0 - r0); m0 = r0; }
        s0 += __expf(r0 - m0);
        if (r1 > m1) { s1 *= __expf(m1 - r1); m1 = r1; }
        s1 += __expf(r1 - m1);
    }
    #pragma unroll
    for (int o = 1; o < 64; o <<= 1) {
        float om0 = __shfl_xor(m0, o), os0 = __shfl_xor(s0, o);
        float nm0 = fmaxf(m0, om0);
        s0 = s0 * __expf(m0 - nm0) + os0 * __expf(om0 - nm0);
        m0 = nm0;
        float om1 = __shfl_xor(m1, o), os1 = __shfl_xor(s1, o);
        float nm1 = fmaxf(m1, om1);
        s1 = s1 * __expf(m1 - nm1) + os1 * __expf(om1 - nm1);
        m1 = nm1;
    }
    float inv0 = 1.f / (s0 + 1e-16f), inv1 = 1.f / (s1 + 1e-16f);

    int sub = lane & 15;        // channel segment
    int g = lane >> 4;          // edge subgroup
    int ch0 = sub * 8;
    int hsel = sub >> 3;        // head of this lane's channels

    float acc[8];
    #pragma unroll
    for (int k = 0; k < 8; k++) acc[k] = 0.f;

    for (int base = start; base < end; base += 64) {
        int cnt = min(64, end - base);
        int s_l = 0;
        float w0_l = 0.f, w1_l = 0.f;
        if (lane < cnt) {
            s_l = srcs[base + lane];
            float2 a = *(const float2*)(asv + 2 * s_l);
            w0_l = __expf(leaky(a.x + ad0) - m0) * inv0;
            w1_l = __expf(leaky(a.y + ad1) - m1) * inv1;
        }
        int steps = (cnt + 3) >> 2;
        for (int jj = 0; jj < steps; ++jj) {
            int e = jj * 4 + g;
            float w0e = __shfl(w0_l, e);
            float w1e = __shfl(w1_l, e);
            int se = __shfl(s_l, e);
            float we = hsel ? w1e : w0e;
            uint4 v = *(const uint4*)(h1 + (size_t)se * 128 + ch0);
            float f0, f1, f2, f3, f4, f5, f6, f7;
            unpack2(v.x, f0, f1);
            unpack2(v.y, f2, f3);
            unpack2(v.z, f4, f5);
            unpack2(v.w, f6, f7);
            acc[0] = fmaf(we, f0, acc[0]);
            acc[1] = fmaf(we, f1, acc[1]);
            acc[2] = fmaf(we, f2, acc[2]);
            acc[3] = fmaf(we, f3, acc[3]);
            acc[4] = fmaf(we, f4, acc[4]);
            acc[5] = fmaf(we, f5, acc[5]);
            acc[6] = fmaf(we, f6, acc[6]);
            acc[7] = fmaf(we, f7, acc[7]);
        }
    }
    // fold the 4 edge subgroups
    #pragma unroll
    for (int o = 16; o < 64; o <<= 1)
        #pragma unroll
        for (int k = 0; k < 8; k++) acc[k] += __shfl_xor(acc[k], o);

    if (lane < 16) {
        float4 b0 = *(const float4*)(bias + ch0);
        float4 b1 = *(const float4*)(bias + ch0 + 4);
        union { __hip_bfloat16 h[8]; uint4 u; } o2;
        o2.h[0] = __float2bfloat16(fmaxf(acc[0] + b0.x, 0.f));
        o2.h[1] = __float2bfloat16(fmaxf(acc[1] + b0.y, 0.f));
        o2.h[2] = __float2bfloat16(fmaxf(acc[2] + b0.z, 0.f));
        o2.h[3] = __float2bfloat16(fmaxf(acc[3] + b0.w, 0.f));
        o2.h[4] = __float2bfloat16(fmaxf(acc[4] + b1.x, 0.f));
        o2.h[5] = __float2bfloat16(fmaxf(acc[5] + b1.y, 0.f));
        o2.h[6] = __float2bfloat16(fmaxf(acc[6] + b1.z, 0.f));
        o2.h[7] = __float2bfloat16(fmaxf(acc[7] + b1.w, 0.f));
        *(uint4*)(out + (size_t)d * 128 + ch0) = o2.u;
    }
}

// ---------------------------------------------------------------------------
// Edge softmax + aggregation, layer 2 (heads=1) + bias + log_softmax.
// Wide gather: 8 lanes x dwordx4 cover one 128-B row -> 8 edges per load.
// ---------------------------------------------------------------------------
__global__ __launch_bounds__(256) void edge_agg_l2(
    const int* __restrict__ offs, const int* __restrict__ srcs,
    const __hip_bfloat16* __restrict__ h2, const float* __restrict__ asv,
    const float* __restrict__ adv, const float* __restrict__ bias,
    float* __restrict__ out, int n) {
    int d = (blockIdx.x * blockDim.x + threadIdx.x) >> 6;
    int lane = threadIdx.x & 63;
    if (d >= n) return;
    int start = offs[d], end = offs[d + 1];
    float ad = adv[d];

    float m = -3.4e38f, ssum = 0.f;
    for (int e = start + lane; e < end; e += 64) {
        int s = srcs[e];
        float r = leaky(asv[s] + ad);
        if (r > m) { ssum *= __expf(m - r); m = r; }
        ssum += __expf(r - m);
    }
    #pragma unroll
    for (int o = 1; o < 64; o <<= 1) {
        float om = __shfl_xor(m, o), os = __shfl_xor(ssum, o);
        float nm = fmaxf(m, om);
        ssum = ssum * __expf(m - nm) + os * __expf(om - nm);
        m = nm;
    }
    float inv = 1.f / (ssum + 1e-16f);

    int sub = lane & 7;        // channel segment (8 ch)
    int g = lane >> 3;         // edge subgroup 0..7
    int ch0 = sub * 8;

    float acc[8];
    #pragma unroll
    for (int k = 0; k < 8; k++) acc[k] = 0.f;

    for (int base = start; base < end; base += 64) {
        int cnt = min(64, end - base);
        int s_l = 0;
        float w_l = 0.f;
        if (lane < cnt) {
            s_l = srcs[base + lane];
            w_l = __expf(leaky(asv[s_l] + ad) - m) * inv;
        }
        int steps = (cnt + 7) >> 3;
        for (int jj = 0; jj < steps; ++jj) {
            int e = jj * 8 + g;
            float we = __shfl(w_l, e);
            int se = __shfl(s_l, e);
            uint4 v = *(const uint4*)(h2 + (size_t)se * 64 + ch0);
            float f0, f1, f2, f3, f4, f5, f6, f7;
            unpack2(v.x, f0, f1);
            unpack2(v.y, f2, f3);
            unpack2(v.z, f4, f5);
            unpack2(v.w, f6, f7);
            acc[0] = fmaf(we, f0, acc[0]);
            acc[1] = fmaf(we, f1, acc[1]);
            acc[2] = fmaf(we, f2, acc[2]);
            acc[3] = fmaf(we, f3, acc[3]);
            acc[4] = fmaf(we, f4, acc[4]);
            acc[5] = fmaf(we, f5, acc[5]);
            acc[6] = fmaf(we, f6, acc[6]);
            acc[7] = fmaf(we, f7, acc[7]);
        }
    }
    // fold the 8 edge subgroups (bits 3..5 of lane)
    #pragma unroll
    for (int o = 8; o < 64; o <<= 1)
        #pragma unroll
        for (int k = 0; k < 8; k++) acc[k] += __shfl_xor(acc[k], o);

    // v = acc + bias ; log_softmax over 64 channels
    float4 b0 = *(const float4*)(bias + ch0);
    float4 b1 = *(const float4*)(bias + ch0 + 4);
    float v[8];
    v[0] = acc[0] + b0.x; v[1] = acc[1] + b0.y;
    v[2] = acc[2] + b0.z; v[3] = acc[3] + b0.w;
    v[4] = acc[4] + b1.x; v[5] = acc[5] + b1.y;
    v[6] = acc[6] + b1.z; v[7] = acc[7] + b1.w;

    float vm = v[0];
    #pragma unroll
    for (int k = 1; k < 8; k++) vm = fmaxf(vm, v[k]);
    #pragma unroll
    for (int o = 1; o < 8; o <<= 1) vm = fmaxf(vm, __shfl_xor(vm, o));
    float se_loc = 0.f;
    #pragma unroll
    for (int k = 0; k < 8; k++) se_loc += __expf(v[k] - vm);
    #pragma unroll
    for (int o = 1; o < 8; o <<= 1) se_loc += __shfl_xor(se_loc, o);
    float lse = vm + logf(se_loc);

    if (lane < 8) {
        float4 o0 = make_float4(v[0] - lse, v[1] - lse, v[2] - lse, v[3] - lse);
        float4 o1 = make_float4(v[4] - lse, v[5] - lse, v[6] - lse, v[7] - lse);
        *(float4*)(out + (size_t)d * 64 + ch0) = o0;
        *(float4*)(out + (size_t)d * 64 + ch0 + 4) = o1;
    }
}

// ---------------------------------------------------------------------------
// Launch
// ---------------------------------------------------------------------------
extern "C" void kernel_launch(void* const* d_in, const int* in_sizes, int n_in,
                              void* d_out, int out_size, void* d_ws, size_t ws_size,
                              hipStream_t stream) {
    const float* x    = (const float*)d_in[0];
    const int*   ei   = (const int*)d_in[1];
    const float* W1   = (const float*)d_in[2];
    const float* as1w = (const float*)d_in[3];
    const float* ad1w = (const float*)d_in[4];
    const float* b1   = (const float*)d_in[5];
    const float* W2   = (const float*)d_in[6];
    const float* as2w = (const float*)d_in[7];
    const float* ad2w = (const float*)d_in[8];
    const float* b2   = (const float*)d_in[9];
    float* out = (float*)d_out;

    const int n = in_sizes[0] / 256;      // 50000
    const int E = in_sizes[1] / 2;        // 1600000
    const int tot = E + n;
    const int nbk = (n + BWIDTH - 1) / BWIDTH;

    char* p = (char*)d_ws;
    auto alloc = [&](size_t bytes) {
        void* r = (void*)p;
        p += (bytes + 255) & ~(size_t)255;
        return r;
    };
    int*   offs  = (int*)alloc((size_t)(n + 1) * 4);
    int*   srcs  = (int*)alloc((size_t)tot * 4);
    int2*  tmp   = (int2*)alloc((size_t)E * 8);
    int*   bcnt  = (int*)alloc(512 * 4);
    int*   bbase = (int*)alloc(512 * 4);
    int*   bcur  = (int*)alloc(512 * 4);
    __hip_bfloat16* W1t = (__hip_bfloat16*)alloc((size_t)128 * 256 * 2);
    __hip_bfloat16* W2t = (__hip_bfloat16*)alloc((size_t)64 * 128 * 2);
    __hip_bfloat16* h1  = (__hip_bfloat16*)alloc((size_t)n * 128 * 2);
    __hip_bfloat16* out1= (__hip_bfloat16*)alloc((size_t)n * 128 * 2);
    __hip_bfloat16* h2  = (__hip_bfloat16*)alloc((size_t)n * 64 * 2);
    float* a_s1 = (float*)alloc((size_t)n * 2 * 4);
    float* a_d1 = (float*)alloc((size_t)n * 2 * 4);
    float* a_s2 = (float*)alloc((size_t)n * 4);
    float* a_d2 = (float*)alloc((size_t)n * 4);

    int pblocks = (E + PCHUNK - 1) / PCHUNK;

    // --- bucketed CSR build ---
    zero_buf<<<2, 256, 0, stream>>>(bcnt, 512);
    bucket_hist<<<pblocks, 256, 0, stream>>>(ei, E, bcnt);
    bucket_scan<<<1, 512, 0, stream>>>(bcnt, bbase, bcur, nbk, n);
    partition_edges<<<pblocks, 256, 0, stream>>>(ei, E, bcur, tmp);
    bucket_csr<<<nbk, 256, 0, stream>>>(bbase, tmp, offs, srcs, n, nbk);

    // --- weight prep ---
    transpose_both<<<(128 * 256 + 64 * 128 + 255) / 256, 256, 0, stream>>>(W1, W2, W1t, W2t);

    // --- Layer 1 ---
    gemm_att<false, 8, 2><<<(n + 63) / 64, 256, 0, stream>>>(
        x, W1t, h1, as1w, ad1w, a_s1, a_d1, n, 256);
    edge_agg_l1<<<(n * 64 + 255) / 256, 256, 0, stream>>>(offs, srcs, h1, a_s1, a_d1, b1, out1, n);

    // --- Layer 2 ---
    gemm_att<true, 4, 1><<<(n + 63) / 64, 256, 0, stream>>>(
        out1, W2t, h2, as2w, ad2w, a_s2, a_d2, n, 128);
    edge_agg_l2<<<(n * 64 + 255) / 256, 256, 0, stream>>>(offs, srcs, h2, a_s2, a_d2, b2, out, n);
}